// Round 4
// baseline (16998.471 us; speedup 1.0000x reference)
//
#include <hip/hip_runtime.h>
#include <cstdint>
#include <cstddef>

#define BATCH 512
#define D_IN 64
#define D_MODEL 768
#define DEPTH 24
#define D_INNER 1536
#define D_STATE 16
#define D_CONV 4
#define DT_RANK 48
#define XDB_DIM 80
#define GRID 512
#define NTHREADS 256

typedef __bf16 bf16x8 __attribute__((ext_vector_type(8)));
typedef unsigned short ushortx8 __attribute__((ext_vector_type(8)));
typedef unsigned short ushortx4 __attribute__((ext_vector_type(4)));
typedef float f32x4 __attribute__((ext_vector_type(4)));
typedef unsigned short ushort_t;

#define XZW_N ((size_t)2 * D_INNER * D_MODEL)   // 2359296 per layer
#define OPW_N ((size_t)D_MODEL * D_INNER)       // 1179648 per layer
#define XZ_G  (long)(XZW_N / 8)                 // 294912 groups
#define OP_G  (long)(OPW_N / 8)                 // 147456 groups
#define TOT_G (XZ_G + OP_G)                     // 442368 groups

struct Args {
    const float *x_t, *in_w, *in_b, *xz_w, *conv_w, *conv_b, *xproj_w, *dtproj_w;
    const float *dtproj_b, *A_log, *Dvec, *outproj_w, *conv_state, *ssm_state, *ln_g, *ln_b;
    float *h, *x, *z, *y, *partial, *out;
    ushort_t *h_hi, *h_lo, *y_hi, *y_lo;
    ushort_t *xzw_hi, *xzw_lo, *opw_hi, *opw_lo;  // [2 slots] each
    unsigned *bar;                                 // bar[0]=cnt, bar[1]=gen
};

__device__ __forceinline__ float sigmoidf_(float v) { return 1.f / (1.f + expf(-v)); }

// Truncation-based fp32 -> bf16 hi/lo split (bit-identical to rounds 2/3).
__device__ __forceinline__ void split1(float f, unsigned short& h, unsigned short& l) {
    unsigned int u = __float_as_uint(f);
    unsigned int uh = u & 0xffff0000u;
    h = (unsigned short)(uh >> 16);
    float r = f - __uint_as_float(uh);
    l = (unsigned short)(__float_as_uint(r) >> 16);
}

__device__ __forceinline__ void split8(const float* s, ushort_t* hi, ushort_t* lo) {
    float4 A4 = *(const float4*)s;
    float4 B4 = *(const float4*)(s + 4);
    float f[8] = {A4.x, A4.y, A4.z, A4.w, B4.x, B4.y, B4.z, B4.w};
    ushortx8 h, l;
#pragma unroll
    for (int j = 0; j < 8; ++j) {
        unsigned short hh, ll;
        split1(f[j], hh, ll);
        h[j] = hh; l[j] = ll;
    }
    *(ushortx8*)hi = h;
    *(ushortx8*)lo = l;
}

// -------- grid barrier (gen-based, device scope). All blocks call in lockstep.
__device__ __forceinline__ void gbar(unsigned* bar, unsigned g) {
    __threadfence();
    __syncthreads();
    if (threadIdx.x == 0) {
        unsigned old = __hip_atomic_fetch_add(&bar[0], 1u, __ATOMIC_ACQ_REL, __HIP_MEMORY_SCOPE_AGENT);
        if (old == GRID - 1) {
            __hip_atomic_store(&bar[0], 0u, __ATOMIC_RELAXED, __HIP_MEMORY_SCOPE_AGENT);
            __hip_atomic_fetch_add(&bar[1], 1u, __ATOMIC_RELEASE, __HIP_MEMORY_SCOPE_AGENT);
        } else {
            while (__hip_atomic_load(&bar[1], __ATOMIC_ACQUIRE, __HIP_MEMORY_SCOPE_AGENT) <= g)
                __builtin_amdgcn_s_sleep(2);
        }
    }
    __syncthreads();
    __threadfence();
}

// -------- phase: split layer-l weights into planes slot (range [g0,g1) of TOT_G)
__device__ void split_layer_range(const Args& a, int l, int slot, int worker,
                                  int nworkers, long g0, long g1) {
    const float* xsrc = a.xz_w + (size_t)l * XZW_N;
    const float* osrc = a.outproj_w + (size_t)l * OPW_N;
    ushort_t* xh = a.xzw_hi + (size_t)slot * XZW_N;
    ushort_t* xl = a.xzw_lo + (size_t)slot * XZW_N;
    ushort_t* oh = a.opw_hi + (size_t)slot * OPW_N;
    ushort_t* ol = a.opw_lo + (size_t)slot * OPW_N;
    for (long g = g0 + (long)worker * NTHREADS + threadIdx.x; g < g1;
         g += (long)nworkers * NTHREADS) {
        if (g < XZ_G) split8(xsrc + g * 8, xh + g * 8, xl + g * 8);
        else {
            long og = g - XZ_G;
            split8(osrc + og * 8, oh + og * 8, ol + og * 8);
        }
    }
}

// -------- phase: in_proj fp32 GEMM (M=512,N=768,K=64), 96 tiles of 64x64
__device__ void inproj_phase(const Args& a, int vt, char* smem) {
    float (*As)[68] = (float (*)[68])smem;
    float (*Ws)[68] = (float (*)[68])(smem + 16 * 68 * 4);
    const int tid = threadIdx.x;
    const int tx = tid & 15, ty = tid >> 4;
    const int bn0 = (vt % 12) * 64, bm0 = (vt / 12) * 64;
    float acc[4][4] = {};
    for (int k0 = 0; k0 < D_IN; k0 += 16) {
        int r = tid >> 2, c = (tid & 3) << 2;
        float4 a4 = *(const float4*)(a.x_t + (size_t)(bm0 + r) * D_IN + k0 + c);
        As[c + 0][r] = a4.x; As[c + 1][r] = a4.y;
        As[c + 2][r] = a4.z; As[c + 3][r] = a4.w;
        float4 w4 = *(const float4*)(a.in_w + (size_t)(bn0 + r) * D_IN + k0 + c);
        Ws[c + 0][r] = w4.x; Ws[c + 1][r] = w4.y;
        Ws[c + 2][r] = w4.z; Ws[c + 3][r] = w4.w;
        __syncthreads();
#pragma unroll
        for (int kk = 0; kk < 16; ++kk) {
            float af[4], wf[4];
#pragma unroll
            for (int i = 0; i < 4; ++i) af[i] = As[kk][ty * 4 + i];
#pragma unroll
            for (int j = 0; j < 4; ++j) wf[j] = Ws[kk][tx * 4 + j];
#pragma unroll
            for (int i = 0; i < 4; ++i)
#pragma unroll
                for (int j = 0; j < 4; ++j) acc[i][j] += af[i] * wf[j];
        }
        __syncthreads();
    }
#pragma unroll
    for (int i = 0; i < 4; ++i) {
        const int bb = bm0 + ty * 4 + i;
#pragma unroll
        for (int j = 0; j < 4; ++j) {
            const int n = bn0 + tx * 4 + j;
            float v = acc[i][j] + a.in_b[n];
            const size_t idx = (size_t)bb * D_MODEL + n;
            a.h[idx] = v;
            unsigned short hh, ll;
            split1(v, hh, ll);
            a.h_hi[idx] = hh;
            a.h_lo[idx] = ll;
        }
    }
}

// -------- phase: bf16x3 MFMA GEMM, 64x64 tile, 4 waves of 32x32, BK=32, dbuf LDS
// MODE 0: xz GEMM (A=h planes K=768, W=xz slot, N=3072) + conv/silu epilogue
// MODE 1: outproj partial (A=y planes K=1536 slice ks*384..+384, W=op slot) -> partial[ks]
template<int MODE>
__device__ void gemm2_phase(const Args& a, int l, int vt, char* smem) {
    const int slot = l & 1;
    int bm0, bn0, K, nk, kofs, ks = 0;
    const ushort_t *Abase_hi, *Abase_lo, *Wbase_hi, *Wbase_lo;
    if (MODE == 0) {
        bn0 = (vt % 48) * 64; bm0 = (vt / 48) * 64;
        K = D_MODEL; nk = D_MODEL / 32; kofs = 0;
        Abase_hi = a.h_hi; Abase_lo = a.h_lo;
        Wbase_hi = a.xzw_hi + (size_t)slot * XZW_N;
        Wbase_lo = a.xzw_lo + (size_t)slot * XZW_N;
    } else {
        const int tile = vt >> 2; ks = vt & 3;
        bn0 = (tile % 12) * 64; bm0 = (tile / 12) * 64;
        K = D_INNER; nk = 12; kofs = ks * 384;
        Abase_hi = a.y_hi; Abase_lo = a.y_lo;
        Wbase_hi = a.opw_hi + (size_t)slot * OPW_N;
        Wbase_lo = a.opw_lo + (size_t)slot * OPW_N;
    }
    ushort_t* AsB = (ushort_t*)smem;             // [2][4096]
    ushort_t* BsB = (ushort_t*)(smem + 16384);   // [2][4096]

    const int t = threadIdx.x;
    const int sr = t >> 2, s0 = t & 3;
    const int lane = t & 63, wv = t >> 6;
    const int wm = wv >> 1, wn = wv & 1;
    const int ln15 = lane & 15, kq = lane >> 4;

    const ushort_t* Ah = Abase_hi + (size_t)(bm0 + sr) * K + kofs + s0 * 8;
    const ushort_t* Al = Abase_lo + (size_t)(bm0 + sr) * K + kofs + s0 * 8;
    const ushort_t* Wh = Wbase_hi + (size_t)(bn0 + sr) * K + kofs + s0 * 8;
    const ushort_t* Wl = Wbase_lo + (size_t)(bn0 + sr) * K + kofs + s0 * 8;

    f32x4 acc[2][2];
#pragma unroll
    for (int m = 0; m < 2; ++m)
#pragma unroll
        for (int n = 0; n < 2; ++n) acc[m][n] = (f32x4){0.f, 0.f, 0.f, 0.f};

    const int sw = sr & 7;
    auto stage = [&](ushortx8 hi, ushortx8 lo, ushort_t* S) {
        *(ushortx8*)&S[sr * 64 + ((s0 ^ sw) << 3)] = hi;
        *(ushortx8*)&S[sr * 64 + (((s0 + 4) ^ sw) << 3)] = lo;
    };

    ushortx8 pah = *(const ushortx8*)Ah;
    ushortx8 pal = *(const ushortx8*)Al;
    ushortx8 pwh = *(const ushortx8*)Wh;
    ushortx8 pwl = *(const ushortx8*)Wl;
    stage(pah, pal, AsB);
    stage(pwh, pwl, BsB);

    for (int kb = 0; kb < nk; ++kb) {
        __syncthreads();
        const int cur = kb & 1;
        if (kb + 1 < nk) {
            const int ko = (kb + 1) << 5;
            pah = *(const ushortx8*)(Ah + ko);
            pal = *(const ushortx8*)(Al + ko);
            pwh = *(const ushortx8*)(Wh + ko);
            pwl = *(const ushortx8*)(Wl + ko);
        }
        bf16x8 ah[2], al[2], bh[2], bl[2];
#pragma unroll
        for (int m = 0; m < 2; ++m) {
            const int r = wm * 32 + m * 16 + ln15;
            const int base = cur * 4096 + r * 64;
            const int rs = r & 7;
            ah[m] = __builtin_bit_cast(bf16x8, *(ushortx8*)&AsB[base + ((kq ^ rs) << 3)]);
            al[m] = __builtin_bit_cast(bf16x8, *(ushortx8*)&AsB[base + (((kq + 4) ^ rs) << 3)]);
        }
#pragma unroll
        for (int n = 0; n < 2; ++n) {
            const int r = wn * 32 + n * 16 + ln15;
            const int base = cur * 4096 + r * 64;
            const int rs = r & 7;
            bh[n] = __builtin_bit_cast(bf16x8, *(ushortx8*)&BsB[base + ((kq ^ rs) << 3)]);
            bl[n] = __builtin_bit_cast(bf16x8, *(ushortx8*)&BsB[base + (((kq + 4) ^ rs) << 3)]);
        }
#pragma unroll
        for (int m = 0; m < 2; ++m)
#pragma unroll
            for (int n = 0; n < 2; ++n) {
                acc[m][n] = __builtin_amdgcn_mfma_f32_16x16x32_bf16(ah[m], bh[n], acc[m][n], 0, 0, 0);
                acc[m][n] = __builtin_amdgcn_mfma_f32_16x16x32_bf16(ah[m], bl[n], acc[m][n], 0, 0, 0);
                acc[m][n] = __builtin_amdgcn_mfma_f32_16x16x32_bf16(al[m], bh[n], acc[m][n], 0, 0, 0);
            }
        if (kb + 1 < nk) {
            stage(pah, pal, AsB + (cur ^ 1) * 4096);
            stage(pwh, pwl, BsB + (cur ^ 1) * 4096);
        }
    }

    // epilogue: C/D frag mapping col=lane&15, row=(lane>>4)*4+j
#pragma unroll
    for (int m = 0; m < 2; ++m) {
#pragma unroll
        for (int n = 0; n < 2; ++n) {
            const int col = bn0 + wn * 32 + n * 16 + ln15;
            const int row0 = bm0 + wm * 32 + m * 16 + kq * 4;
            f32x4 v = acc[m][n];
            if (MODE == 0) {
                const float* csl = a.conv_state + (size_t)l * BATCH * D_INNER * D_CONV;
                const float* cwl = a.conv_w + (size_t)l * D_INNER * D_CONV;
                const float* cbl = a.conv_b + (size_t)l * D_INNER;
                if (col < D_INNER) {
                    const float4 cwv = *(const float4*)(cwl + (size_t)col * 4);
                    const float cbv = cbl[col];
#pragma unroll
                    for (int j = 0; j < 4; ++j) {
                        const int row = row0 + j;
                        const float4 csv = *(const float4*)(csl + ((size_t)row * D_INNER + col) * 4);
                        float c = csv.y * cwv.x + csv.z * cwv.y + csv.w * cwv.z
                                + v[j] * cwv.w + cbv;
                        a.x[(size_t)row * D_INNER + col] = c * sigmoidf_(c);
                    }
                } else {
#pragma unroll
                    for (int j = 0; j < 4; ++j)
                        a.z[(size_t)(row0 + j) * D_INNER + (col - D_INNER)] = v[j];
                }
            } else {
                float* pp = a.partial + (size_t)ks * BATCH * D_MODEL;
#pragma unroll
                for (int j = 0; j < 4; ++j)
                    pp[(size_t)(row0 + j) * D_MODEL + col] = v[j];
            }
        }
    }
}

// -------- phase: fused xproj + dt + softplus + SSM + gate; one block per batch row
__device__ void bc_phase(const Args& a, int l, int b, char* smem) {
    float* xs = (float*)smem;               // 1536 floats
    float* xdb = (float*)(smem + 6144);     // 80 floats
    const int tid = threadIdx.x;
    const float* xpl = a.xproj_w + (size_t)l * XDB_DIM * D_INNER;
    const float* dwl = a.dtproj_w + (size_t)l * D_INNER * DT_RANK;
    const float* dbl = a.dtproj_b + (size_t)l * D_INNER;
    const float* all = a.A_log + (size_t)l * D_INNER * D_STATE;
    const float* dpl = a.Dvec + (size_t)l * D_INNER;
    const float* ssl = a.ssm_state + (size_t)l * BATCH * D_INNER * D_STATE;

    const float4* xrow = (const float4*)(a.x + (size_t)b * D_INNER);
    float4* xs4 = (float4*)xs;
    for (int i = tid; i < D_INNER / 4; i += NTHREADS) xs4[i] = xrow[i];
    __syncthreads();

    const int lane = tid & 63;
    const int wv = tid >> 6;
    for (int n = wv; n < XDB_DIM; n += 4) {
        const float4* wr = (const float4*)(xpl + (size_t)n * D_INNER);
        float s = 0.f;
#pragma unroll
        for (int j = 0; j < D_INNER / 4 / 64; ++j) {
            float4 w = wr[lane + 64 * j];
            float4 xv = xs4[lane + 64 * j];
            s += w.x * xv.x + w.y * xv.y + w.z * xv.z + w.w * xv.w;
        }
#pragma unroll
        for (int off = 32; off > 0; off >>= 1) s += __shfl_xor(s, off);
        if (lane == 0) xdb[n] = s;
    }
    __syncthreads();

    float Bmv[D_STATE], Cv[D_STATE];
#pragma unroll
    for (int n = 0; n < D_STATE; ++n) {
        Bmv[n] = xdb[DT_RANK + n];
        Cv[n] = xdb[DT_RANK + D_STATE + n];
    }

    for (int d = tid; d < D_INNER; d += NTHREADS) {
        const float4* dtw = (const float4*)(dwl + (size_t)d * DT_RANK);
        float s = 0.f;
#pragma unroll
        for (int j = 0; j < DT_RANK / 4; ++j) {
            float4 w = dtw[j];
            s += w.x * xdb[4 * j + 0] + w.y * xdb[4 * j + 1]
               + w.z * xdb[4 * j + 2] + w.w * xdb[4 * j + 3];
        }
        s += dbl[d];
        float dt = fmaxf(s, 0.f) + log1pf(expf(-fabsf(s)));
        float xv = xs[d];
        float dtx = dt * xv;

        const float4* ssp = (const float4*)(ssl + ((size_t)b * D_INNER + d) * D_STATE);
        const float4* alp = (const float4*)(all + (size_t)d * D_STATE);
        float yacc = 0.f;
#pragma unroll
        for (int q = 0; q < 4; ++q) {
            float4 al4 = alp[q];
            float4 sv = ssp[q];
            float e0 = expf(-dt * expf(al4.x));
            float e1 = expf(-dt * expf(al4.y));
            float e2 = expf(-dt * expf(al4.z));
            float e3 = expf(-dt * expf(al4.w));
            yacc += (sv.x * e0 + dtx * Bmv[4 * q + 0]) * Cv[4 * q + 0];
            yacc += (sv.y * e1 + dtx * Bmv[4 * q + 1]) * Cv[4 * q + 1];
            yacc += (sv.z * e2 + dtx * Bmv[4 * q + 2]) * Cv[4 * q + 2];
            yacc += (sv.w * e3 + dtx * Bmv[4 * q + 3]) * Cv[4 * q + 3];
        }
        yacc += dpl[d] * xv;
        float zv = a.z[(size_t)b * D_INNER + d];
        float out = yacc * (zv * sigmoidf_(zv));
        const size_t idx = (size_t)b * D_INNER + d;
        a.y[idx] = out;
        unsigned short hh, ll;
        split1(out, hh, ll);
        a.y_hi[idx] = hh;
        a.y_lo[idx] = ll;
    }
}

// -------- phase: reduce 4 outproj partials -> h + split planes
__device__ void reduce_phase(const Args& a, int b) {
    const int total4 = BATCH * D_MODEL / 4;  // 98304
    const f32x4* p0 = (const f32x4*)a.partial;
    const f32x4* p1 = p0 + total4;
    const f32x4* p2 = p1 + total4;
    const f32x4* p3 = p2 + total4;
    f32x4* h4 = (f32x4*)a.h;
    for (int i = b * NTHREADS + threadIdx.x; i < total4; i += GRID * NTHREADS) {
        f32x4 s = p0[i] + p1[i] + p2[i] + p3[i];
        h4[i] = s;
        ushortx4 hv, lv;
#pragma unroll
        for (int j = 0; j < 4; ++j) {
            unsigned short hh, ll;
            split1(s[j], hh, ll);
            hv[j] = hh; lv[j] = ll;
        }
        *(ushortx4*)(a.h_hi + (size_t)i * 4) = hv;
        *(ushortx4*)(a.h_lo + (size_t)i * 4) = lv;
    }
}

// -------- phase: LayerNorm, one block per row
__device__ void ln_phase(const Args& a, int b, char* smem) {
    float* red = (float*)smem;
    const int tid = threadIdx.x;
    float v[3];
#pragma unroll
    for (int j = 0; j < 3; ++j) v[j] = a.h[(size_t)b * D_MODEL + tid + j * 256];
    float s = v[0] + v[1] + v[2];
    float s2 = v[0] * v[0] + v[1] * v[1] + v[2] * v[2];
#pragma unroll
    for (int off = 32; off > 0; off >>= 1) {
        s += __shfl_xor(s, off);
        s2 += __shfl_xor(s2, off);
    }
    const int lane = tid & 63, wv = tid >> 6;
    if (lane == 0) { red[wv] = s; red[4 + wv] = s2; }
    __syncthreads();
    s = red[0] + red[1] + red[2] + red[3];
    s2 = red[4] + red[5] + red[6] + red[7];
    const float mu = s * (1.f / D_MODEL);
    const float var = s2 * (1.f / D_MODEL) - mu * mu;
    const float inv = 1.f / sqrtf(var + 1e-5f);
#pragma unroll
    for (int j = 0; j < 3; ++j) {
        int c = tid + j * 256;
        a.out[(size_t)b * D_MODEL + c] = (v[j] - mu) * inv * a.ln_g[c] + a.ln_b[c];
    }
}

// ================= persistent cooperative kernel =================
__global__ __launch_bounds__(NTHREADS, 2) void persist(Args a) {
    __shared__ __align__(16) char smem[32768];
    const int b = blockIdx.x;
    unsigned bars = 0;

    if (b < 96) inproj_phase(a, b, smem);
    else split_layer_range(a, 0, 0, b - 96, GRID - 96, 0, TOT_G);
    gbar(a.bar, bars); ++bars;

    for (int l = 0; l < DEPTH; ++l) {
        if (b < 384) gemm2_phase<0>(a, l, b, smem);
        else if (l + 1 < DEPTH)
            split_layer_range(a, l + 1, (l + 1) & 1, b - 384, 128, 0, TOT_G / 2);
        gbar(a.bar, bars); ++bars;

        bc_phase(a, l, b, smem);
        gbar(a.bar, bars); ++bars;

        if (b < 384) gemm2_phase<1>(a, l, b, smem);
        else if (l + 1 < DEPTH)
            split_layer_range(a, l + 1, (l + 1) & 1, b - 384, 128, TOT_G / 2, TOT_G);
        gbar(a.bar, bars); ++bars;

        reduce_phase(a, b);
        gbar(a.bar, bars); ++bars;
    }

    ln_phase(a, b, smem);
}

// ================= fallback wrappers (regular launches, same device code) ====
__global__ __launch_bounds__(64) void k_init(unsigned* bar) {
    if (threadIdx.x < 2) bar[threadIdx.x] = 0;
}
__global__ __launch_bounds__(NTHREADS) void k_inproj(Args a) {
    __shared__ __align__(16) char smem[32768];
    inproj_phase(a, blockIdx.x, smem);
}
__global__ __launch_bounds__(NTHREADS) void k_split(Args a, int l, int slot) {
    split_layer_range(a, l, slot, blockIdx.x, gridDim.x, 0, TOT_G);
}
__global__ __launch_bounds__(NTHREADS) void k_xz(Args a, int l) {
    __shared__ __align__(16) char smem[32768];
    gemm2_phase<0>(a, l, blockIdx.x, smem);
}
__global__ __launch_bounds__(NTHREADS) void k_bc(Args a, int l) {
    __shared__ __align__(16) char smem[32768];
    bc_phase(a, l, blockIdx.x, smem);
}
__global__ __launch_bounds__(NTHREADS) void k_op(Args a, int l) {
    __shared__ __align__(16) char smem[32768];
    gemm2_phase<1>(a, l, blockIdx.x, smem);
}
__global__ __launch_bounds__(NTHREADS) void k_red(Args a) {
    reduce_phase(a, blockIdx.x);
}
__global__ __launch_bounds__(NTHREADS) void k_ln(Args a) {
    __shared__ __align__(16) char smem[32768];
    ln_phase(a, blockIdx.x, smem);
}

extern "C" void kernel_launch(void* const* d_in, const int* in_sizes, int n_in,
                              void* d_out, int out_size, void* d_ws, size_t ws_size,
                              hipStream_t stream)
{
    char* wsb = (char*)d_ws;
    unsigned* bar = (unsigned*)wsb;                 // 64 B reserved
    float* h = (float*)(wsb + 64);
    float* x = h + (size_t)BATCH * D_MODEL;
    float* z = x + (size_t)BATCH * D_INNER;
    float* y = z + (size_t)BATCH * D_INNER;
    float* partial = y + (size_t)BATCH * D_INNER;   // 4 * 512*768
    ushort_t* h_hi = (ushort_t*)(partial + (size_t)4 * BATCH * D_MODEL);
    ushort_t* h_lo = h_hi + (size_t)BATCH * D_MODEL;
    ushort_t* y_hi = h_lo + (size_t)BATCH * D_MODEL;
    ushort_t* y_lo = y_hi + (size_t)BATCH * D_INNER;
    ushort_t* xzw_hi = y_lo + (size_t)BATCH * D_INNER;    // 2 slots
    ushort_t* xzw_lo = xzw_hi + 2 * XZW_N;
    ushort_t* opw_hi = xzw_lo + 2 * XZW_N;
    ushort_t* opw_lo = opw_hi + 2 * OPW_N;

    Args args;
    args.x_t        = (const float*)d_in[0];
    args.in_w       = (const float*)d_in[1];
    args.in_b       = (const float*)d_in[2];
    args.xz_w       = (const float*)d_in[3];
    args.conv_w     = (const float*)d_in[4];
    args.conv_b     = (const float*)d_in[5];
    args.xproj_w    = (const float*)d_in[6];
    args.dtproj_w   = (const float*)d_in[7];
    args.dtproj_b   = (const float*)d_in[8];
    args.A_log      = (const float*)d_in[9];
    args.Dvec       = (const float*)d_in[10];
    args.outproj_w  = (const float*)d_in[11];
    args.conv_state = (const float*)d_in[12];
    args.ssm_state  = (const float*)d_in[13];
    args.ln_g       = (const float*)d_in[14];
    args.ln_b       = (const float*)d_in[15];
    args.h = h; args.x = x; args.z = z; args.y = y; args.partial = partial;
    args.out = (float*)d_out;
    args.h_hi = h_hi; args.h_lo = h_lo; args.y_hi = y_hi; args.y_lo = y_lo;
    args.xzw_hi = xzw_hi; args.xzw_lo = xzw_lo;
    args.opw_hi = opw_hi; args.opw_lo = opw_lo;
    args.bar = bar;

    k_init<<<dim3(1), dim3(64), 0, stream>>>(bar);

    void* kp[] = { &args };
    hipError_t e = hipLaunchCooperativeKernel((const void*)persist, dim3(GRID),
                                              dim3(NTHREADS), kp, 0, stream);
    if (e != hipSuccess) {
        (void)hipGetLastError();  // clear
        // Fallback: sequential multi-kernel path (same device code).
        k_inproj<<<dim3(96), dim3(NTHREADS), 0, stream>>>(args);
        for (int l = 0; l < DEPTH; ++l) {
            k_split<<<dim3(512), dim3(NTHREADS), 0, stream>>>(args, l, l & 1);
            k_xz<<<dim3(384), dim3(NTHREADS), 0, stream>>>(args, l);
            k_bc<<<dim3(512), dim3(NTHREADS), 0, stream>>>(args, l);
            k_op<<<dim3(384), dim3(NTHREADS), 0, stream>>>(args, l);
            k_red<<<dim3(512), dim3(NTHREADS), 0, stream>>>(args);
        }
        k_ln<<<dim3(512), dim3(NTHREADS), 0, stream>>>(args);
    }
}

// Round 5
// 6822.953 us; speedup vs baseline: 2.4914x; 2.4914x over previous
//
#include <hip/hip_runtime.h>
#include <cstdint>
#include <cstddef>

#define BATCH 512
#define D_IN 64
#define D_MODEL 768
#define DEPTH 24
#define D_INNER 1536
#define D_STATE 16
#define D_CONV 4
#define DT_RANK 48
#define XDB_DIM 80
#define GRID 512
#define NTHREADS 256

typedef __bf16 bf16x8 __attribute__((ext_vector_type(8)));
typedef unsigned short ushortx8 __attribute__((ext_vector_type(8)));
typedef unsigned short ushortx4 __attribute__((ext_vector_type(4)));
typedef float f32x4 __attribute__((ext_vector_type(4)));
typedef unsigned short ushort_t;

#define XZW_N ((size_t)2 * D_INNER * D_MODEL)   // 2359296 per layer
#define OPW_N ((size_t)D_MODEL * D_INNER)       // 1179648 per layer
#define XZ_G  (long)(XZW_N / 8)                 // 294912 groups
#define OP_G  (long)(OPW_N / 8)                 // 147456 groups
#define TOT_G (XZ_G + OP_G)                     // 442368 groups
#define SPLIT1 (TOT_G / 4)                      // chunk done during xz phase

struct Args {
    const float *x_t, *in_w, *in_b, *xz_w, *conv_w, *conv_b, *xproj_w, *dtproj_w;
    const float *dtproj_b, *A_log, *Dvec, *outproj_w, *conv_state, *ssm_state, *ln_g, *ln_b;
    float *h, *x, *z, *y, *out;
    ushort_t *h_hi, *h_lo, *y_hi, *y_lo;
    ushort_t *xzw_hi, *xzw_lo, *opw_hi, *opw_lo;  // [2 slots] each
    unsigned *bar;                                 // bar[0]=cnt, bar[1]=gen
};

__device__ __forceinline__ float sigmoidf_(float v) { return 1.f / (1.f + expf(-v)); }

// Truncation-based fp32 -> bf16 hi/lo split (bit-identical to rounds 2-4).
__device__ __forceinline__ void split1(float f, unsigned short& h, unsigned short& l) {
    unsigned int u = __float_as_uint(f);
    unsigned int uh = u & 0xffff0000u;
    h = (unsigned short)(uh >> 16);
    float r = f - __uint_as_float(uh);
    l = (unsigned short)(__float_as_uint(r) >> 16);
}

__device__ __forceinline__ void split8(const float* s, ushort_t* hi, ushort_t* lo) {
    float4 A4 = *(const float4*)s;
    float4 B4 = *(const float4*)(s + 4);
    float f[8] = {A4.x, A4.y, A4.z, A4.w, B4.x, B4.y, B4.z, B4.w};
    ushortx8 h, l;
#pragma unroll
    for (int j = 0; j < 8; ++j) {
        unsigned short hh, ll;
        split1(f[j], hh, ll);
        h[j] = hh; l[j] = ll;
    }
    *(ushortx8*)hi = h;
    *(ushortx8*)lo = l;
}

// -------- grid barrier: RELAXED spin (no per-poll cache ops), ONE release fence
// before arrival and ONE acquire fence after the generation bump is observed.
// Agent-scope fences on CDNA4 = per-XCD L2 wb/inv, so they must be O(1) per
// barrier per block, never inside the poll loop (round-4 lesson: 136us/barrier).
__device__ __forceinline__ void gbar(unsigned* bar, unsigned g) {
    __syncthreads();
    if (threadIdx.x == 0) {
        __builtin_amdgcn_fence(__ATOMIC_RELEASE, "agent");
        unsigned old = __hip_atomic_fetch_add(&bar[0], 1u, __ATOMIC_RELAXED,
                                              __HIP_MEMORY_SCOPE_AGENT);
        if (old == GRID - 1) {
            __builtin_amdgcn_fence(__ATOMIC_ACQUIRE, "agent");
            __hip_atomic_store(&bar[0], 0u, __ATOMIC_RELAXED, __HIP_MEMORY_SCOPE_AGENT);
            __builtin_amdgcn_fence(__ATOMIC_RELEASE, "agent");
            __hip_atomic_store(&bar[1], g + 1u, __ATOMIC_RELAXED, __HIP_MEMORY_SCOPE_AGENT);
        } else {
            while (__hip_atomic_load(&bar[1], __ATOMIC_RELAXED,
                                     __HIP_MEMORY_SCOPE_AGENT) <= g)
                __builtin_amdgcn_s_sleep(4);
            __builtin_amdgcn_fence(__ATOMIC_ACQUIRE, "agent");
        }
    }
    __syncthreads();
}

// -------- phase: split layer-l weights into planes slot (range [g0,g1) of TOT_G)
__device__ void split_layer_range(const Args& a, int l, int slot, int worker,
                                  int nworkers, long g0, long g1) {
    const float* xsrc = a.xz_w + (size_t)l * XZW_N;
    const float* osrc = a.outproj_w + (size_t)l * OPW_N;
    ushort_t* xh = a.xzw_hi + (size_t)slot * XZW_N;
    ushort_t* xl = a.xzw_lo + (size_t)slot * XZW_N;
    ushort_t* oh = a.opw_hi + (size_t)slot * OPW_N;
    ushort_t* ol = a.opw_lo + (size_t)slot * OPW_N;
    for (long g = g0 + (long)worker * NTHREADS + threadIdx.x; g < g1;
         g += (long)nworkers * NTHREADS) {
        if (g < XZ_G) split8(xsrc + g * 8, xh + g * 8, xl + g * 8);
        else {
            long og = g - XZ_G;
            split8(osrc + og * 8, oh + og * 8, ol + og * 8);
        }
    }
}

// -------- phase: in_proj fp32 GEMM (M=512,N=768,K=64), 96 tiles of 64x64
__device__ void inproj_phase(const Args& a, int vt, char* smem) {
    float (*As)[68] = (float (*)[68])smem;
    float (*Ws)[68] = (float (*)[68])(smem + 16 * 68 * 4);
    const int tid = threadIdx.x;
    const int tx = tid & 15, ty = tid >> 4;
    const int bn0 = (vt % 12) * 64, bm0 = (vt / 12) * 64;
    float acc[4][4] = {};
    for (int k0 = 0; k0 < D_IN; k0 += 16) {
        int r = tid >> 2, c = (tid & 3) << 2;
        float4 a4 = *(const float4*)(a.x_t + (size_t)(bm0 + r) * D_IN + k0 + c);
        As[c + 0][r] = a4.x; As[c + 1][r] = a4.y;
        As[c + 2][r] = a4.z; As[c + 3][r] = a4.w;
        float4 w4 = *(const float4*)(a.in_w + (size_t)(bn0 + r) * D_IN + k0 + c);
        Ws[c + 0][r] = w4.x; Ws[c + 1][r] = w4.y;
        Ws[c + 2][r] = w4.z; Ws[c + 3][r] = w4.w;
        __syncthreads();
#pragma unroll
        for (int kk = 0; kk < 16; ++kk) {
            float af[4], wf[4];
#pragma unroll
            for (int i = 0; i < 4; ++i) af[i] = As[kk][ty * 4 + i];
#pragma unroll
            for (int j = 0; j < 4; ++j) wf[j] = Ws[kk][tx * 4 + j];
#pragma unroll
            for (int i = 0; i < 4; ++i)
#pragma unroll
                for (int j = 0; j < 4; ++j) acc[i][j] += af[i] * wf[j];
        }
        __syncthreads();
    }
#pragma unroll
    for (int i = 0; i < 4; ++i) {
        const int bb = bm0 + ty * 4 + i;
#pragma unroll
        for (int j = 0; j < 4; ++j) {
            const int n = bn0 + tx * 4 + j;
            float v = acc[i][j] + a.in_b[n];
            const size_t idx = (size_t)bb * D_MODEL + n;
            a.h[idx] = v;
            unsigned short hh, ll;
            split1(v, hh, ll);
            a.h_hi[idx] = hh;
            a.h_lo[idx] = ll;
        }
    }
}

// -------- phase: bf16x3 MFMA GEMM, 64x64 tile, 4 waves of 32x32, BK=32, dbuf LDS
// MODE 0: xz GEMM (A=h planes K=768, W=xz slot, 384 tiles) + conv/silu epilogue
// MODE 1: outproj (A=y planes K=1536, W=op slot, 96 tiles) -> h + split planes
template<int MODE>
__device__ void gemm2_phase(const Args& a, int l, int vt, char* smem) {
    const int slot = l & 1;
    int bm0, bn0, K, nk;
    const ushort_t *Abase_hi, *Abase_lo, *Wbase_hi, *Wbase_lo;
    if (MODE == 0) {
        bn0 = (vt % 48) * 64; bm0 = (vt / 48) * 64;
        K = D_MODEL; nk = D_MODEL / 32;
        Abase_hi = a.h_hi; Abase_lo = a.h_lo;
        Wbase_hi = a.xzw_hi + (size_t)slot * XZW_N;
        Wbase_lo = a.xzw_lo + (size_t)slot * XZW_N;
    } else {
        bn0 = (vt % 12) * 64; bm0 = (vt / 12) * 64;
        K = D_INNER; nk = D_INNER / 32;
        Abase_hi = a.y_hi; Abase_lo = a.y_lo;
        Wbase_hi = a.opw_hi + (size_t)slot * OPW_N;
        Wbase_lo = a.opw_lo + (size_t)slot * OPW_N;
    }
    ushort_t* AsB = (ushort_t*)smem;             // [2][4096]
    ushort_t* BsB = (ushort_t*)(smem + 16384);   // [2][4096]

    const int t = threadIdx.x;
    const int sr = t >> 2, s0 = t & 3;
    const int lane = t & 63, wv = t >> 6;
    const int wm = wv >> 1, wn = wv & 1;
    const int ln15 = lane & 15, kq = lane >> 4;

    const ushort_t* Ah = Abase_hi + (size_t)(bm0 + sr) * K + s0 * 8;
    const ushort_t* Al = Abase_lo + (size_t)(bm0 + sr) * K + s0 * 8;
    const ushort_t* Wh = Wbase_hi + (size_t)(bn0 + sr) * K + s0 * 8;
    const ushort_t* Wl = Wbase_lo + (size_t)(bn0 + sr) * K + s0 * 8;

    f32x4 acc[2][2];
#pragma unroll
    for (int m = 0; m < 2; ++m)
#pragma unroll
        for (int n = 0; n < 2; ++n) acc[m][n] = (f32x4){0.f, 0.f, 0.f, 0.f};

    const int sw = sr & 7;
    auto stage = [&](ushortx8 hi, ushortx8 lo, ushort_t* S) {
        *(ushortx8*)&S[sr * 64 + ((s0 ^ sw) << 3)] = hi;
        *(ushortx8*)&S[sr * 64 + (((s0 + 4) ^ sw) << 3)] = lo;
    };

    ushortx8 pah = *(const ushortx8*)Ah;
    ushortx8 pal = *(const ushortx8*)Al;
    ushortx8 pwh = *(const ushortx8*)Wh;
    ushortx8 pwl = *(const ushortx8*)Wl;
    stage(pah, pal, AsB);
    stage(pwh, pwl, BsB);

    for (int kb = 0; kb < nk; ++kb) {
        __syncthreads();
        const int cur = kb & 1;
        if (kb + 1 < nk) {
            const int ko = (kb + 1) << 5;
            pah = *(const ushortx8*)(Ah + ko);
            pal = *(const ushortx8*)(Al + ko);
            pwh = *(const ushortx8*)(Wh + ko);
            pwl = *(const ushortx8*)(Wl + ko);
        }
        bf16x8 ah[2], al[2], bh[2], bl[2];
#pragma unroll
        for (int m = 0; m < 2; ++m) {
            const int r = wm * 32 + m * 16 + ln15;
            const int base = cur * 4096 + r * 64;
            const int rs = r & 7;
            ah[m] = __builtin_bit_cast(bf16x8, *(ushortx8*)&AsB[base + ((kq ^ rs) << 3)]);
            al[m] = __builtin_bit_cast(bf16x8, *(ushortx8*)&AsB[base + (((kq + 4) ^ rs) << 3)]);
        }
#pragma unroll
        for (int n = 0; n < 2; ++n) {
            const int r = wn * 32 + n * 16 + ln15;
            const int base = cur * 4096 + r * 64;
            const int rs = r & 7;
            bh[n] = __builtin_bit_cast(bf16x8, *(ushortx8*)&BsB[base + ((kq ^ rs) << 3)]);
            bl[n] = __builtin_bit_cast(bf16x8, *(ushortx8*)&BsB[base + (((kq + 4) ^ rs) << 3)]);
        }
#pragma unroll
        for (int m = 0; m < 2; ++m)
#pragma unroll
            for (int n = 0; n < 2; ++n) {
                acc[m][n] = __builtin_amdgcn_mfma_f32_16x16x32_bf16(ah[m], bh[n], acc[m][n], 0, 0, 0);
                acc[m][n] = __builtin_amdgcn_mfma_f32_16x16x32_bf16(ah[m], bl[n], acc[m][n], 0, 0, 0);
                acc[m][n] = __builtin_amdgcn_mfma_f32_16x16x32_bf16(al[m], bh[n], acc[m][n], 0, 0, 0);
            }
        if (kb + 1 < nk) {
            stage(pah, pal, AsB + (cur ^ 1) * 4096);
            stage(pwh, pwl, BsB + (cur ^ 1) * 4096);
        }
    }

    // epilogue: C/D frag mapping col=lane&15, row=(lane>>4)*4+j
#pragma unroll
    for (int m = 0; m < 2; ++m) {
#pragma unroll
        for (int n = 0; n < 2; ++n) {
            const int col = bn0 + wn * 32 + n * 16 + ln15;
            const int row0 = bm0 + wm * 32 + m * 16 + kq * 4;
            f32x4 v = acc[m][n];
            if (MODE == 0) {
                const float* csl = a.conv_state + (size_t)l * BATCH * D_INNER * D_CONV;
                const float* cwl = a.conv_w + (size_t)l * D_INNER * D_CONV;
                const float* cbl = a.conv_b + (size_t)l * D_INNER;
                if (col < D_INNER) {
                    const float4 cwv = *(const float4*)(cwl + (size_t)col * 4);
                    const float cbv = cbl[col];
#pragma unroll
                    for (int j = 0; j < 4; ++j) {
                        const int row = row0 + j;
                        const float4 csv = *(const float4*)(csl + ((size_t)row * D_INNER + col) * 4);
                        float c = csv.y * cwv.x + csv.z * cwv.y + csv.w * cwv.z
                                + v[j] * cwv.w + cbv;
                        a.x[(size_t)row * D_INNER + col] = c * sigmoidf_(c);
                    }
                } else {
#pragma unroll
                    for (int j = 0; j < 4; ++j)
                        a.z[(size_t)(row0 + j) * D_INNER + (col - D_INNER)] = v[j];
                }
            } else {
#pragma unroll
                for (int j = 0; j < 4; ++j) {
                    const size_t idx = (size_t)(row0 + j) * D_MODEL + col;
                    float val = v[j];
                    a.h[idx] = val;
                    unsigned short hh, ll;
                    split1(val, hh, ll);
                    a.h_hi[idx] = hh;
                    a.h_lo[idx] = ll;
                }
            }
        }
    }
}

// -------- phase: fused xproj + dt + softplus + SSM + gate; one block per batch row
__device__ void bc_phase(const Args& a, int l, int b, char* smem) {
    float* xs = (float*)smem;               // 1536 floats
    float* xdb = (float*)(smem + 6144);     // 80 floats
    const int tid = threadIdx.x;
    const float* xpl = a.xproj_w + (size_t)l * XDB_DIM * D_INNER;
    const float* dwl = a.dtproj_w + (size_t)l * D_INNER * DT_RANK;
    const float* dbl = a.dtproj_b + (size_t)l * D_INNER;
    const float* all = a.A_log + (size_t)l * D_INNER * D_STATE;
    const float* dpl = a.Dvec + (size_t)l * D_INNER;
    const float* ssl = a.ssm_state + (size_t)l * BATCH * D_INNER * D_STATE;

    const float4* xrow = (const float4*)(a.x + (size_t)b * D_INNER);
    float4* xs4 = (float4*)xs;
    for (int i = tid; i < D_INNER / 4; i += NTHREADS) xs4[i] = xrow[i];
    __syncthreads();

    const int lane = tid & 63;
    const int wv = tid >> 6;
    for (int n = wv; n < XDB_DIM; n += 4) {
        const float4* wr = (const float4*)(xpl + (size_t)n * D_INNER);
        float s = 0.f;
#pragma unroll
        for (int j = 0; j < D_INNER / 4 / 64; ++j) {
            float4 w = wr[lane + 64 * j];
            float4 xv = xs4[lane + 64 * j];
            s += w.x * xv.x + w.y * xv.y + w.z * xv.z + w.w * xv.w;
        }
#pragma unroll
        for (int off = 32; off > 0; off >>= 1) s += __shfl_xor(s, off);
        if (lane == 0) xdb[n] = s;
    }
    __syncthreads();

    float Bmv[D_STATE], Cv[D_STATE];
#pragma unroll
    for (int n = 0; n < D_STATE; ++n) {
        Bmv[n] = xdb[DT_RANK + n];
        Cv[n] = xdb[DT_RANK + D_STATE + n];
    }

    for (int d = tid; d < D_INNER; d += NTHREADS) {
        const float4* dtw = (const float4*)(dwl + (size_t)d * DT_RANK);
        float s = 0.f;
#pragma unroll
        for (int j = 0; j < DT_RANK / 4; ++j) {
            float4 w = dtw[j];
            s += w.x * xdb[4 * j + 0] + w.y * xdb[4 * j + 1]
               + w.z * xdb[4 * j + 2] + w.w * xdb[4 * j + 3];
        }
        s += dbl[d];
        float dt = fmaxf(s, 0.f) + log1pf(expf(-fabsf(s)));
        float xv = xs[d];
        float dtx = dt * xv;

        const float4* ssp = (const float4*)(ssl + ((size_t)b * D_INNER + d) * D_STATE);
        const float4* alp = (const float4*)(all + (size_t)d * D_STATE);
        float yacc = 0.f;
#pragma unroll
        for (int q = 0; q < 4; ++q) {
            float4 al4 = alp[q];
            float4 sv = ssp[q];
            float e0 = expf(-dt * expf(al4.x));
            float e1 = expf(-dt * expf(al4.y));
            float e2 = expf(-dt * expf(al4.z));
            float e3 = expf(-dt * expf(al4.w));
            yacc += (sv.x * e0 + dtx * Bmv[4 * q + 0]) * Cv[4 * q + 0];
            yacc += (sv.y * e1 + dtx * Bmv[4 * q + 1]) * Cv[4 * q + 1];
            yacc += (sv.z * e2 + dtx * Bmv[4 * q + 2]) * Cv[4 * q + 2];
            yacc += (sv.w * e3 + dtx * Bmv[4 * q + 3]) * Cv[4 * q + 3];
        }
        yacc += dpl[d] * xv;
        float zv = a.z[(size_t)b * D_INNER + d];
        float out = yacc * (zv * sigmoidf_(zv));
        const size_t idx = (size_t)b * D_INNER + d;
        a.y[idx] = out;
        unsigned short hh, ll;
        split1(out, hh, ll);
        a.y_hi[idx] = hh;
        a.y_lo[idx] = ll;
    }
}

// -------- phase: LayerNorm, one block per row
__device__ void ln_phase(const Args& a, int b, char* smem) {
    float* red = (float*)smem;
    const int tid = threadIdx.x;
    float v[3];
#pragma unroll
    for (int j = 0; j < 3; ++j) v[j] = a.h[(size_t)b * D_MODEL + tid + j * 256];
    float s = v[0] + v[1] + v[2];
    float s2 = v[0] * v[0] + v[1] * v[1] + v[2] * v[2];
#pragma unroll
    for (int off = 32; off > 0; off >>= 1) {
        s += __shfl_xor(s, off);
        s2 += __shfl_xor(s2, off);
    }
    const int lane = tid & 63, wv = tid >> 6;
    if (lane == 0) { red[wv] = s; red[4 + wv] = s2; }
    __syncthreads();
    s = red[0] + red[1] + red[2] + red[3];
    s2 = red[4] + red[5] + red[6] + red[7];
    const float mu = s * (1.f / D_MODEL);
    const float var = s2 * (1.f / D_MODEL) - mu * mu;
    const float inv = 1.f / sqrtf(var + 1e-5f);
#pragma unroll
    for (int j = 0; j < 3; ++j) {
        int c = tid + j * 256;
        a.out[(size_t)b * D_MODEL + c] = (v[j] - mu) * inv * a.ln_g[c] + a.ln_b[c];
    }
}

// ================= persistent cooperative kernel =================
__global__ __launch_bounds__(NTHREADS, 2) void persist(Args a) {
    __shared__ __align__(16) char smem[32768];
    const int b = blockIdx.x;
    unsigned bars = 0;

    if (b < 96) inproj_phase(a, b, smem);
    else split_layer_range(a, 0, 0, b - 96, GRID - 96, 0, TOT_G);
    gbar(a.bar, bars); ++bars;

    for (int l = 0; l < DEPTH; ++l) {
        if (b < 384) gemm2_phase<0>(a, l, b, smem);
        else if (l + 1 < DEPTH)
            split_layer_range(a, l + 1, (l + 1) & 1, b - 384, 128, 0, SPLIT1);
        gbar(a.bar, bars); ++bars;

        bc_phase(a, l, b, smem);
        gbar(a.bar, bars); ++bars;

        if (b < 96) gemm2_phase<1>(a, l, b, smem);
        else if (l + 1 < DEPTH)
            split_layer_range(a, l + 1, (l + 1) & 1, b - 96, 416, SPLIT1, TOT_G);
        gbar(a.bar, bars); ++bars;
    }

    ln_phase(a, b, smem);
}

// ================= fallback wrappers (regular launches, same device code) ====
__global__ __launch_bounds__(64) void k_init(unsigned* bar) {
    if (threadIdx.x < 2) bar[threadIdx.x] = 0;
}
__global__ __launch_bounds__(NTHREADS) void k_inproj(Args a) {
    __shared__ __align__(16) char smem[32768];
    inproj_phase(a, blockIdx.x, smem);
}
__global__ __launch_bounds__(NTHREADS) void k_split(Args a, int l, int slot) {
    split_layer_range(a, l, slot, blockIdx.x, gridDim.x, 0, TOT_G);
}
__global__ __launch_bounds__(NTHREADS) void k_xz(Args a, int l) {
    __shared__ __align__(16) char smem[32768];
    gemm2_phase<0>(a, l, blockIdx.x, smem);
}
__global__ __launch_bounds__(NTHREADS) void k_bc(Args a, int l) {
    __shared__ __align__(16) char smem[32768];
    bc_phase(a, l, blockIdx.x, smem);
}
__global__ __launch_bounds__(NTHREADS) void k_op(Args a, int l) {
    __shared__ __align__(16) char smem[32768];
    gemm2_phase<1>(a, l, blockIdx.x, smem);
}
__global__ __launch_bounds__(NTHREADS) void k_ln(Args a) {
    __shared__ __align__(16) char smem[32768];
    ln_phase(a, blockIdx.x, smem);
}

extern "C" void kernel_launch(void* const* d_in, const int* in_sizes, int n_in,
                              void* d_out, int out_size, void* d_ws, size_t ws_size,
                              hipStream_t stream)
{
    char* wsb = (char*)d_ws;
    unsigned* bar = (unsigned*)wsb;                 // 64 B reserved
    float* h = (float*)(wsb + 64);
    float* x = h + (size_t)BATCH * D_MODEL;
    float* z = x + (size_t)BATCH * D_INNER;
    float* y = z + (size_t)BATCH * D_INNER;
    ushort_t* h_hi = (ushort_t*)(y + (size_t)BATCH * D_INNER);
    ushort_t* h_lo = h_hi + (size_t)BATCH * D_MODEL;
    ushort_t* y_hi = h_lo + (size_t)BATCH * D_MODEL;
    ushort_t* y_lo = y_hi + (size_t)BATCH * D_INNER;
    ushort_t* xzw_hi = y_lo + (size_t)BATCH * D_INNER;    // 2 slots
    ushort_t* xzw_lo = xzw_hi + 2 * XZW_N;
    ushort_t* opw_hi = xzw_lo + 2 * XZW_N;
    ushort_t* opw_lo = opw_hi + 2 * OPW_N;

    Args args;
    args.x_t        = (const float*)d_in[0];
    args.in_w       = (const float*)d_in[1];
    args.in_b       = (const float*)d_in[2];
    args.xz_w       = (const float*)d_in[3];
    args.conv_w     = (const float*)d_in[4];
    args.conv_b     = (const float*)d_in[5];
    args.xproj_w    = (const float*)d_in[6];
    args.dtproj_w   = (const float*)d_in[7];
    args.dtproj_b   = (const float*)d_in[8];
    args.A_log      = (const float*)d_in[9];
    args.Dvec       = (const float*)d_in[10];
    args.outproj_w  = (const float*)d_in[11];
    args.conv_state = (const float*)d_in[12];
    args.ssm_state  = (const float*)d_in[13];
    args.ln_g       = (const float*)d_in[14];
    args.ln_b       = (const float*)d_in[15];
    args.h = h; args.x = x; args.z = z; args.y = y;
    args.out = (float*)d_out;
    args.h_hi = h_hi; args.h_lo = h_lo; args.y_hi = y_hi; args.y_lo = y_lo;
    args.xzw_hi = xzw_hi; args.xzw_lo = xzw_lo;
    args.opw_hi = opw_hi; args.opw_lo = opw_lo;
    args.bar = bar;

    k_init<<<dim3(1), dim3(64), 0, stream>>>(bar);

    void* kp[] = { &args };
    hipError_t e = hipLaunchCooperativeKernel((const void*)persist, dim3(GRID),
                                              dim3(NTHREADS), kp, 0, stream);
    if (e != hipSuccess) {
        (void)hipGetLastError();  // clear
        // Fallback: sequential multi-kernel path (same device code).
        k_inproj<<<dim3(96), dim3(NTHREADS), 0, stream>>>(args);
        for (int l = 0; l < DEPTH; ++l) {
            k_split<<<dim3(512), dim3(NTHREADS), 0, stream>>>(args, l, l & 1);
            k_xz<<<dim3(384), dim3(NTHREADS), 0, stream>>>(args, l);
            k_bc<<<dim3(512), dim3(NTHREADS), 0, stream>>>(args, l);
            k_op<<<dim3(96), dim3(NTHREADS), 0, stream>>>(args, l);
        }
        k_ln<<<dim3(512), dim3(NTHREADS), 0, stream>>>(args);
    }
}

// Round 6
// 5146.018 us; speedup vs baseline: 3.3032x; 1.3259x over previous
//
#include <hip/hip_runtime.h>
#include <cstdint>
#include <cstddef>

#define BATCH 512
#define D_IN 64
#define D_MODEL 768
#define DEPTH 24
#define D_INNER 1536
#define D_STATE 16
#define D_CONV 4
#define DT_RANK 48
#define XDB_DIM 80
#define GRID 512
#define NTHREADS 256

typedef __bf16 bf16x8 __attribute__((ext_vector_type(8)));
typedef unsigned short ushortx8 __attribute__((ext_vector_type(8)));
typedef unsigned short ushortx4 __attribute__((ext_vector_type(4)));
typedef float f32x4 __attribute__((ext_vector_type(4)));
typedef unsigned short ushort_t;
typedef unsigned long long u64_t;

#define XZW_N ((size_t)2 * D_INNER * D_MODEL)
#define OPW_N ((size_t)D_MODEL * D_INNER)
#define XZ_G  (long)(XZW_N / 8)
#define OP_G  (long)(OPW_N / 8)
#define TOT_G (XZ_G + OP_G)

struct Args {
    const float *x_t, *in_w, *in_b, *xz_w, *conv_w, *conv_b, *xproj_w, *dtproj_w;
    const float *dtproj_b, *A_log, *Dvec, *outproj_w, *conv_state, *ssm_state, *ln_g, *ln_b;
    float *h, *x, *z, *out;
    ushort_t *h_hi, *h_lo, *y_hi, *y_lo;
    ushort_t *xzw_hi, *xzw_lo, *opw_hi, *opw_lo;  // full DEPTH-sized planes
    unsigned *cnt;                                 // monotonic barrier counter
};

__device__ __forceinline__ float sigmoidf_(float v) { return 1.f / (1.f + expf(-v)); }

// ---- coherent (MALL-level) accessors: agent-scope relaxed atomics bypass the
// non-coherent L1/L2 per-instruction. No cache fences anywhere in this kernel.
__device__ __forceinline__ float cload(const float* p) {
    return __hip_atomic_load((float*)p, __ATOMIC_RELAXED, __HIP_MEMORY_SCOPE_AGENT);
}
__device__ __forceinline__ void cstore(float* p, float v) {
    __hip_atomic_store(p, v, __ATOMIC_RELAXED, __HIP_MEMORY_SCOPE_AGENT);
}
__device__ __forceinline__ void cstore16(ushort_t* p, ushort_t v) {
    __hip_atomic_store(p, v, __ATOMIC_RELAXED, __HIP_MEMORY_SCOPE_AGENT);
}
__device__ __forceinline__ u64_t cload64(const void* p) {
    return __hip_atomic_load((u64_t*)p, __ATOMIC_RELAXED, __HIP_MEMORY_SCOPE_AGENT);
}
__device__ __forceinline__ void cstore64(void* p, u64_t v) {
    __hip_atomic_store((u64_t*)p, v, __ATOMIC_RELAXED, __HIP_MEMORY_SCOPE_AGENT);
}
__device__ __forceinline__ ushortx8 cload8x16(const ushort_t* p) {
    u64_t a = cload64(p);
    u64_t b = cload64(p + 4);
    ushortx4 lo = __builtin_bit_cast(ushortx4, a);
    ushortx4 hi = __builtin_bit_cast(ushortx4, b);
    ushortx8 r;
    r[0] = lo[0]; r[1] = lo[1]; r[2] = lo[2]; r[3] = lo[3];
    r[4] = hi[0]; r[5] = hi[1]; r[6] = hi[2]; r[7] = hi[3];
    return r;
}
__device__ __forceinline__ float4 cloadf4(const float* p) {
    u64_t a = cload64(p);
    u64_t b = cload64(p + 2);
    float2 x = __builtin_bit_cast(float2, a);
    float2 y = __builtin_bit_cast(float2, b);
    return make_float4(x.x, x.y, y.x, y.y);
}

// Truncation-based fp32 -> bf16 hi/lo split (bit-identical to rounds 2-5).
__device__ __forceinline__ void split1(float f, unsigned short& h, unsigned short& l) {
    unsigned int u = __float_as_uint(f);
    unsigned int uh = u & 0xffff0000u;
    h = (unsigned short)(uh >> 16);
    float r = f - __uint_as_float(uh);
    l = (unsigned short)(__float_as_uint(r) >> 16);
}

__device__ __forceinline__ void split8_c(const float* s, ushort_t* hi, ushort_t* lo) {
    float4 A4 = *(const float4*)s;
    float4 B4 = *(const float4*)(s + 4);
    float f[8] = {A4.x, A4.y, A4.z, A4.w, B4.x, B4.y, B4.z, B4.w};
    ushortx4 h0, h1, l0, l1;
#pragma unroll
    for (int j = 0; j < 4; ++j) { unsigned short hh, ll; split1(f[j], hh, ll); h0[j] = hh; l0[j] = ll; }
#pragma unroll
    for (int j = 0; j < 4; ++j) { unsigned short hh, ll; split1(f[4 + j], hh, ll); h1[j] = hh; l1[j] = ll; }
    cstore64(hi,     __builtin_bit_cast(u64_t, h0));
    cstore64(hi + 4, __builtin_bit_cast(u64_t, h1));
    cstore64(lo,     __builtin_bit_cast(u64_t, l0));
    cstore64(lo + 4, __builtin_bit_cast(u64_t, l1));
}

// ---- fenceless grid barrier: monotonic counter at MALL, relaxed everywhere.
// __syncthreads() drains each wave's vmcnt (coherent stores complete at MALL
// before arrival); readers use coherent loads, so no cache maintenance needed.
__device__ __forceinline__ void gbar(unsigned* cnt, unsigned target) {
    __syncthreads();
    if (threadIdx.x == 0) {
        __hip_atomic_fetch_add(cnt, 1u, __ATOMIC_RELAXED, __HIP_MEMORY_SCOPE_AGENT);
        while (__hip_atomic_load(cnt, __ATOMIC_RELAXED, __HIP_MEMORY_SCOPE_AGENT) < target)
            __builtin_amdgcn_s_sleep(8);
    }
    __syncthreads();
}

// ---- one-time: split ALL layers' xz/outproj weights into bf16 hi/lo planes
__device__ void split_all(const Args& a, int worker, int nworkers) {
    const long total = (long)DEPTH * TOT_G;
    for (long g = (long)worker * NTHREADS + threadIdx.x; g < total;
         g += (long)nworkers * NTHREADS) {
        const int l = (int)(g / TOT_G);
        long r = g - (long)l * TOT_G;
        if (r < XZ_G) {
            const float* src = a.xz_w + (size_t)l * XZW_N + r * 8;
            split8_c(src, a.xzw_hi + (size_t)l * XZW_N + r * 8,
                          a.xzw_lo + (size_t)l * XZW_N + r * 8);
        } else {
            r -= XZ_G;
            const float* src = a.outproj_w + (size_t)l * OPW_N + r * 8;
            split8_c(src, a.opw_hi + (size_t)l * OPW_N + r * 8,
                          a.opw_lo + (size_t)l * OPW_N + r * 8);
        }
    }
}

// ---- in_proj fp32 GEMM (M=512,N=768,K=64), 96 tiles of 64x64
__device__ void inproj_phase(const Args& a, int vt, char* smem) {
    float (*As)[68] = (float (*)[68])smem;
    float (*Ws)[68] = (float (*)[68])(smem + 16 * 68 * 4);
    const int tid = threadIdx.x;
    const int tx = tid & 15, ty = tid >> 4;
    const int bn0 = (vt % 12) * 64, bm0 = (vt / 12) * 64;
    float acc[4][4] = {};
    for (int k0 = 0; k0 < D_IN; k0 += 16) {
        int r = tid >> 2, c = (tid & 3) << 2;
        float4 a4 = *(const float4*)(a.x_t + (size_t)(bm0 + r) * D_IN + k0 + c);
        As[c + 0][r] = a4.x; As[c + 1][r] = a4.y;
        As[c + 2][r] = a4.z; As[c + 3][r] = a4.w;
        float4 w4 = *(const float4*)(a.in_w + (size_t)(bn0 + r) * D_IN + k0 + c);
        Ws[c + 0][r] = w4.x; Ws[c + 1][r] = w4.y;
        Ws[c + 2][r] = w4.z; Ws[c + 3][r] = w4.w;
        __syncthreads();
#pragma unroll
        for (int kk = 0; kk < 16; ++kk) {
            float af[4], wf[4];
#pragma unroll
            for (int i = 0; i < 4; ++i) af[i] = As[kk][ty * 4 + i];
#pragma unroll
            for (int j = 0; j < 4; ++j) wf[j] = Ws[kk][tx * 4 + j];
#pragma unroll
            for (int i = 0; i < 4; ++i)
#pragma unroll
                for (int j = 0; j < 4; ++j) acc[i][j] += af[i] * wf[j];
        }
        __syncthreads();
    }
#pragma unroll
    for (int i = 0; i < 4; ++i) {
        const int bb = bm0 + ty * 4 + i;
#pragma unroll
        for (int j = 0; j < 4; ++j) {
            const int n = bn0 + tx * 4 + j;
            float v = acc[i][j] + a.in_b[n];
            const size_t idx = (size_t)bb * D_MODEL + n;
            cstore(a.h + idx, v);
            unsigned short hh, ll;
            split1(v, hh, ll);
            cstore16(a.h_hi + idx, hh);
            cstore16(a.h_lo + idx, ll);
        }
    }
}

// LDS physical-slot swizzle: p(r,c) = ((c&3)^((r>>1)&3)) + 4*((c>>2)^(r&1)).
// <=2-way (free) on both ds_write_b128 and ds_read_b128 sides.
__device__ __forceinline__ int slotmap(int r, int c) {
    return ((c & 3) ^ ((r >> 1) & 3)) + (((c >> 2) ^ (r & 1)) << 2);
}

// ---- bf16x3 MFMA GEMM, 64x64 tile, 4 waves of 32x32, BK=32, dbuf LDS.
// MODE 0: xz (A=h planes coherent, W=xz planes cached) + conv/silu epilogue
// MODE 1: outproj (A=y planes coherent, W=op planes cached) -> h + planes
template<int MODE>
__device__ void gemm2_phase(const Args& a, int l, int vt, char* smem) {
    int bm0, bn0, K, nk;
    const ushort_t *Abase_hi, *Abase_lo, *Wbase_hi, *Wbase_lo;
    if (MODE == 0) {
        bn0 = (vt % 48) * 64; bm0 = (vt / 48) * 64;
        K = D_MODEL; nk = D_MODEL / 32;
        Abase_hi = a.h_hi; Abase_lo = a.h_lo;
        Wbase_hi = a.xzw_hi + (size_t)l * XZW_N;
        Wbase_lo = a.xzw_lo + (size_t)l * XZW_N;
    } else {
        bn0 = (vt % 12) * 64; bm0 = (vt / 12) * 64;
        K = D_INNER; nk = D_INNER / 32;
        Abase_hi = a.y_hi; Abase_lo = a.y_lo;
        Wbase_hi = a.opw_hi + (size_t)l * OPW_N;
        Wbase_lo = a.opw_lo + (size_t)l * OPW_N;
    }
    ushort_t* AsB = (ushort_t*)smem;             // [2][4096]
    ushort_t* BsB = (ushort_t*)(smem + 16384);   // [2][4096]

    const int t = threadIdx.x;
    const int sr = t >> 2, s0 = t & 3;
    const int lane = t & 63, wv = t >> 6;
    const int wm = wv >> 1, wn = wv & 1;
    const int ln15 = lane & 15, kq = lane >> 4;

    const ushort_t* Ah = Abase_hi + (size_t)(bm0 + sr) * K + s0 * 8;
    const ushort_t* Al = Abase_lo + (size_t)(bm0 + sr) * K + s0 * 8;
    const ushort_t* Wh = Wbase_hi + (size_t)(bn0 + sr) * K + s0 * 8;
    const ushort_t* Wl = Wbase_lo + (size_t)(bn0 + sr) * K + s0 * 8;

    f32x4 acc[2][2];
#pragma unroll
    for (int m = 0; m < 2; ++m)
#pragma unroll
        for (int n = 0; n < 2; ++n) acc[m][n] = (f32x4){0.f, 0.f, 0.f, 0.f};

    const int wslot_hi = slotmap(sr, s0) << 3;
    const int wslot_lo = slotmap(sr, s0 + 4) << 3;
    auto stage = [&](ushortx8 hi, ushortx8 lo, ushort_t* S) {
        *(ushortx8*)&S[sr * 64 + wslot_hi] = hi;
        *(ushortx8*)&S[sr * 64 + wslot_lo] = lo;
    };

    ushortx8 pah = cload8x16(Ah);
    ushortx8 pal = cload8x16(Al);
    ushortx8 pwh = *(const ushortx8*)Wh;
    ushortx8 pwl = *(const ushortx8*)Wl;
    stage(pah, pal, AsB);
    stage(pwh, pwl, BsB);

    for (int kb = 0; kb < nk; ++kb) {
        __syncthreads();
        const int cur = kb & 1;
        if (kb + 1 < nk) {
            const int ko = (kb + 1) << 5;
            pah = cload8x16(Ah + ko);
            pal = cload8x16(Al + ko);
            pwh = *(const ushortx8*)(Wh + ko);
            pwl = *(const ushortx8*)(Wl + ko);
        }
        bf16x8 ah[2], al[2], bh[2], bl[2];
#pragma unroll
        for (int m = 0; m < 2; ++m) {
            const int r = wm * 32 + m * 16 + ln15;
            const int base = cur * 4096 + r * 64;
            ah[m] = __builtin_bit_cast(bf16x8, *(ushortx8*)&AsB[base + (slotmap(r, kq) << 3)]);
            al[m] = __builtin_bit_cast(bf16x8, *(ushortx8*)&AsB[base + (slotmap(r, kq + 4) << 3)]);
        }
#pragma unroll
        for (int n = 0; n < 2; ++n) {
            const int r = wn * 32 + n * 16 + ln15;
            const int base = cur * 4096 + r * 64;
            bh[n] = __builtin_bit_cast(bf16x8, *(ushortx8*)&BsB[base + (slotmap(r, kq) << 3)]);
            bl[n] = __builtin_bit_cast(bf16x8, *(ushortx8*)&BsB[base + (slotmap(r, kq + 4) << 3)]);
        }
#pragma unroll
        for (int m = 0; m < 2; ++m)
#pragma unroll
            for (int n = 0; n < 2; ++n) {
                acc[m][n] = __builtin_amdgcn_mfma_f32_16x16x32_bf16(ah[m], bh[n], acc[m][n], 0, 0, 0);
                acc[m][n] = __builtin_amdgcn_mfma_f32_16x16x32_bf16(ah[m], bl[n], acc[m][n], 0, 0, 0);
                acc[m][n] = __builtin_amdgcn_mfma_f32_16x16x32_bf16(al[m], bh[n], acc[m][n], 0, 0, 0);
            }
        if (kb + 1 < nk) {
            stage(pah, pal, AsB + (cur ^ 1) * 4096);
            stage(pwh, pwl, BsB + (cur ^ 1) * 4096);
        }
    }

    // epilogue: C/D frag mapping col=lane&15, row=(lane>>4)*4+j
#pragma unroll
    for (int m = 0; m < 2; ++m) {
#pragma unroll
        for (int n = 0; n < 2; ++n) {
            const int col = bn0 + wn * 32 + n * 16 + ln15;
            const int row0 = bm0 + wm * 32 + m * 16 + kq * 4;
            f32x4 v = acc[m][n];
            if (MODE == 0) {
                const float* csl = a.conv_state + (size_t)l * BATCH * D_INNER * D_CONV;
                const float* cwl = a.conv_w + (size_t)l * D_INNER * D_CONV;
                const float* cbl = a.conv_b + (size_t)l * D_INNER;
                if (col < D_INNER) {
                    const float4 cwv = *(const float4*)(cwl + (size_t)col * 4);
                    const float cbv = cbl[col];
#pragma unroll
                    for (int j = 0; j < 4; ++j) {
                        const int row = row0 + j;
                        const float4 csv = *(const float4*)(csl + ((size_t)row * D_INNER + col) * 4);
                        float c = csv.y * cwv.x + csv.z * cwv.y + csv.w * cwv.z
                                + v[j] * cwv.w + cbv;
                        cstore(a.x + (size_t)row * D_INNER + col, c * sigmoidf_(c));
                    }
                } else {
#pragma unroll
                    for (int j = 0; j < 4; ++j)
                        cstore(a.z + (size_t)(row0 + j) * D_INNER + (col - D_INNER), v[j]);
                }
            } else {
#pragma unroll
                for (int j = 0; j < 4; ++j) {
                    const size_t idx = (size_t)(row0 + j) * D_MODEL + col;
                    float val = v[j];
                    cstore(a.h + idx, val);
                    unsigned short hh, ll;
                    split1(val, hh, ll);
                    cstore16(a.h_hi + idx, hh);
                    cstore16(a.h_lo + idx, ll);
                }
            }
        }
    }
}

// ---- fused xproj + dt + softplus + SSM + gate; one block per batch row
__device__ void bc_phase(const Args& a, int l, int b, char* smem) {
    float* xs = (float*)smem;               // 1536 floats
    float* xdb = (float*)(smem + 6144);     // 80 floats
    const int tid = threadIdx.x;
    const float* xpl = a.xproj_w + (size_t)l * XDB_DIM * D_INNER;
    const float* dwl = a.dtproj_w + (size_t)l * D_INNER * DT_RANK;
    const float* dbl = a.dtproj_b + (size_t)l * D_INNER;
    const float* all = a.A_log + (size_t)l * D_INNER * D_STATE;
    const float* dpl = a.Dvec + (size_t)l * D_INNER;
    const float* ssl = a.ssm_state + (size_t)l * BATCH * D_INNER * D_STATE;

    const float* xrow = a.x + (size_t)b * D_INNER;
    float4* xs4 = (float4*)xs;
    for (int i = tid; i < D_INNER / 4; i += NTHREADS) xs4[i] = cloadf4(xrow + i * 4);
    __syncthreads();

    const int lane = tid & 63;
    const int wv = tid >> 6;
    for (int n = wv; n < XDB_DIM; n += 4) {
        const float4* wr = (const float4*)(xpl + (size_t)n * D_INNER);
        float s = 0.f;
#pragma unroll
        for (int j = 0; j < D_INNER / 4 / 64; ++j) {
            float4 w = wr[lane + 64 * j];
            float4 xv = xs4[lane + 64 * j];
            s += w.x * xv.x + w.y * xv.y + w.z * xv.z + w.w * xv.w;
        }
#pragma unroll
        for (int off = 32; off > 0; off >>= 1) s += __shfl_xor(s, off);
        if (lane == 0) xdb[n] = s;
    }
    __syncthreads();

    float Bmv[D_STATE], Cv[D_STATE];
#pragma unroll
    for (int n = 0; n < D_STATE; ++n) {
        Bmv[n] = xdb[DT_RANK + n];
        Cv[n] = xdb[DT_RANK + D_STATE + n];
    }

    for (int d = tid; d < D_INNER; d += NTHREADS) {
        const float4* dtw = (const float4*)(dwl + (size_t)d * DT_RANK);
        float s = 0.f;
#pragma unroll
        for (int j = 0; j < DT_RANK / 4; ++j) {
            float4 w = dtw[j];
            s += w.x * xdb[4 * j + 0] + w.y * xdb[4 * j + 1]
               + w.z * xdb[4 * j + 2] + w.w * xdb[4 * j + 3];
        }
        s += dbl[d];
        float dt = fmaxf(s, 0.f) + log1pf(expf(-fabsf(s)));
        float xv = xs[d];
        float dtx = dt * xv;

        const float4* ssp = (const float4*)(ssl + ((size_t)b * D_INNER + d) * D_STATE);
        const float4* alp = (const float4*)(all + (size_t)d * D_STATE);
        float yacc = 0.f;
#pragma unroll
        for (int q = 0; q < 4; ++q) {
            float4 al4 = alp[q];
            float4 sv = ssp[q];
            float e0 = expf(-dt * expf(al4.x));
            float e1 = expf(-dt * expf(al4.y));
            float e2 = expf(-dt * expf(al4.z));
            float e3 = expf(-dt * expf(al4.w));
            yacc += (sv.x * e0 + dtx * Bmv[4 * q + 0]) * Cv[4 * q + 0];
            yacc += (sv.y * e1 + dtx * Bmv[4 * q + 1]) * Cv[4 * q + 1];
            yacc += (sv.z * e2 + dtx * Bmv[4 * q + 2]) * Cv[4 * q + 2];
            yacc += (sv.w * e3 + dtx * Bmv[4 * q + 3]) * Cv[4 * q + 3];
        }
        yacc += dpl[d] * xv;
        float zv = cload(a.z + (size_t)b * D_INNER + d);
        float out = yacc * (zv * sigmoidf_(zv));
        const size_t idx = (size_t)b * D_INNER + d;
        unsigned short hh, ll;
        split1(out, hh, ll);
        cstore16(a.y_hi + idx, hh);
        cstore16(a.y_lo + idx, ll);
    }
}

// ---- LayerNorm, one block per row
__device__ void ln_phase(const Args& a, int b, char* smem) {
    float* red = (float*)smem;
    const int tid = threadIdx.x;
    float v[3];
#pragma unroll
    for (int j = 0; j < 3; ++j) v[j] = cload(a.h + (size_t)b * D_MODEL + tid + j * 256);
    float s = v[0] + v[1] + v[2];
    float s2 = v[0] * v[0] + v[1] * v[1] + v[2] * v[2];
#pragma unroll
    for (int off = 32; off > 0; off >>= 1) {
        s += __shfl_xor(s, off);
        s2 += __shfl_xor(s2, off);
    }
    const int lane = tid & 63, wv = tid >> 6;
    if (lane == 0) { red[wv] = s; red[4 + wv] = s2; }
    __syncthreads();
    s = red[0] + red[1] + red[2] + red[3];
    s2 = red[4] + red[5] + red[6] + red[7];
    const float mu = s * (1.f / D_MODEL);
    const float var = s2 * (1.f / D_MODEL) - mu * mu;
    const float inv = 1.f / sqrtf(var + 1e-5f);
#pragma unroll
    for (int j = 0; j < 3; ++j) {
        int c = tid + j * 256;
        a.out[(size_t)b * D_MODEL + c] = (v[j] - mu) * inv * a.ln_g[c] + a.ln_b[c];
    }
}

// ================= persistent cooperative kernel =================
__global__ __launch_bounds__(NTHREADS, 2) void persist(Args a) {
    __shared__ __align__(16) char smem[32768];
    const int b = blockIdx.x;
    unsigned tgt = 0;

    if (b < 96) inproj_phase(a, b, smem);
    split_all(a, b, GRID);
    tgt += GRID; gbar(a.cnt, tgt);

    for (int l = 0; l < DEPTH; ++l) {
        if (b < 384) gemm2_phase<0>(a, l, b, smem);
        tgt += GRID; gbar(a.cnt, tgt);

        bc_phase(a, l, b, smem);
        tgt += GRID; gbar(a.cnt, tgt);

        if (b < 96) gemm2_phase<1>(a, l, b, smem);
        tgt += GRID; gbar(a.cnt, tgt);
    }

    ln_phase(a, b, smem);
}

// ================= fallback wrappers (regular launches, same device code) ====
__global__ __launch_bounds__(64) void k_init(unsigned* cnt) {
    if (threadIdx.x == 0) *cnt = 0;
}
__global__ __launch_bounds__(NTHREADS) void k_pre(Args a) {
    __shared__ __align__(16) char smem[32768];
    if (blockIdx.x < 96) inproj_phase(a, blockIdx.x, smem);
    split_all(a, blockIdx.x, gridDim.x);
}
__global__ __launch_bounds__(NTHREADS) void k_xz(Args a, int l) {
    __shared__ __align__(16) char smem[32768];
    gemm2_phase<0>(a, l, blockIdx.x, smem);
}
__global__ __launch_bounds__(NTHREADS) void k_bc(Args a, int l) {
    __shared__ __align__(16) char smem[32768];
    bc_phase(a, l, blockIdx.x, smem);
}
__global__ __launch_bounds__(NTHREADS) void k_op(Args a, int l) {
    __shared__ __align__(16) char smem[32768];
    gemm2_phase<1>(a, l, blockIdx.x, smem);
}
__global__ __launch_bounds__(NTHREADS) void k_ln(Args a) {
    __shared__ __align__(16) char smem[32768];
    ln_phase(a, blockIdx.x, smem);
}

extern "C" void kernel_launch(void* const* d_in, const int* in_sizes, int n_in,
                              void* d_out, int out_size, void* d_ws, size_t ws_size,
                              hipStream_t stream)
{
    char* wsb = (char*)d_ws;
    unsigned* cnt = (unsigned*)wsb;                 // 256 B reserved
    float* h = (float*)(wsb + 256);
    float* x = h + (size_t)BATCH * D_MODEL;
    float* z = x + (size_t)BATCH * D_INNER;
    ushort_t* h_hi = (ushort_t*)(z + (size_t)BATCH * D_INNER);
    ushort_t* h_lo = h_hi + (size_t)BATCH * D_MODEL;
    ushort_t* y_hi = h_lo + (size_t)BATCH * D_MODEL;
    ushort_t* y_lo = y_hi + (size_t)BATCH * D_INNER;
    ushort_t* xzw_hi = y_lo + (size_t)BATCH * D_INNER;   // DEPTH-sized planes
    ushort_t* xzw_lo = xzw_hi + (size_t)DEPTH * XZW_N;
    ushort_t* opw_hi = xzw_lo + (size_t)DEPTH * XZW_N;
    ushort_t* opw_lo = opw_hi + (size_t)DEPTH * OPW_N;

    Args args;
    args.x_t        = (const float*)d_in[0];
    args.in_w       = (const float*)d_in[1];
    args.in_b       = (const float*)d_in[2];
    args.xz_w       = (const float*)d_in[3];
    args.conv_w     = (const float*)d_in[4];
    args.conv_b     = (const float*)d_in[5];
    args.xproj_w    = (const float*)d_in[6];
    args.dtproj_w   = (const float*)d_in[7];
    args.dtproj_b   = (const float*)d_in[8];
    args.A_log      = (const float*)d_in[9];
    args.Dvec       = (const float*)d_in[10];
    args.outproj_w  = (const float*)d_in[11];
    args.conv_state = (const float*)d_in[12];
    args.ssm_state  = (const float*)d_in[13];
    args.ln_g       = (const float*)d_in[14];
    args.ln_b       = (const float*)d_in[15];
    args.h = h; args.x = x; args.z = z;
    args.out = (float*)d_out;
    args.h_hi = h_hi; args.h_lo = h_lo; args.y_hi = y_hi; args.y_lo = y_lo;
    args.xzw_hi = xzw_hi; args.xzw_lo = xzw_lo;
    args.opw_hi = opw_hi; args.opw_lo = opw_lo;
    args.cnt = cnt;

    k_init<<<dim3(1), dim3(64), 0, stream>>>(cnt);

    void* kp[] = { &args };
    hipError_t e = hipLaunchCooperativeKernel((const void*)persist, dim3(GRID),
                                              dim3(NTHREADS), kp, 0, stream);
    if (e != hipSuccess) {
        (void)hipGetLastError();  // clear
        // Fallback: sequential multi-kernel path (same device code).
        k_pre<<<dim3(512), dim3(NTHREADS), 0, stream>>>(args);
        for (int l = 0; l < DEPTH; ++l) {
            k_xz<<<dim3(384), dim3(NTHREADS), 0, stream>>>(args, l);
            k_bc<<<dim3(512), dim3(NTHREADS), 0, stream>>>(args, l);
            k_op<<<dim3(96), dim3(NTHREADS), 0, stream>>>(args, l);
        }
        k_ln<<<dim3(512), dim3(NTHREADS), 0, stream>>>(args);
    }
}

// Round 8
// 2498.352 us; speedup vs baseline: 6.8039x; 2.0598x over previous
//
#include <hip/hip_runtime.h>
#include <cstdint>
#include <cstddef>

#define BATCH 512
#define D_IN 64
#define D_MODEL 768
#define DEPTH 24
#define D_INNER 1536
#define D_STATE 16
#define D_CONV 4
#define DT_RANK 48
#define XDB_DIM 80

typedef __bf16 bf16x8 __attribute__((ext_vector_type(8)));
typedef unsigned short ushortx8 __attribute__((ext_vector_type(8)));
typedef float f32x4 __attribute__((ext_vector_type(4)));
typedef unsigned short ushort_t;

#define XZW_N ((size_t)2 * D_INNER * D_MODEL)   // per-layer xz_w elems
#define OPW_N ((size_t)D_MODEL * D_INNER)       // per-layer outproj_w elems
#define XZ_ALL ((long)DEPTH * (long)(XZW_N / 8))
#define OP_ALL ((long)DEPTH * (long)(OPW_N / 8))
#define AN_ALL ((long)DEPTH * D_INNER * D_STATE / 8)

__device__ __forceinline__ float sigmoidf_(float v) { return 1.f / (1.f + __expf(-v)); }

// Truncation-based fp32 -> bf16 hi/lo split (bit-identical to rounds 2-3).
__device__ __forceinline__ void split1(float f, unsigned short& h, unsigned short& l) {
    unsigned int u = __float_as_uint(f);
    unsigned int uh = u & 0xffff0000u;
    h = (unsigned short)(uh >> 16);
    float r = f - __uint_as_float(uh);
    l = (unsigned short)(__float_as_uint(r) >> 16);
}

__device__ __forceinline__ void split8(const float* s, ushort_t* hi, ushort_t* lo) {
    float4 A4 = *(const float4*)s;
    float4 B4 = *(const float4*)(s + 4);
    float f[8] = {A4.x, A4.y, A4.z, A4.w, B4.x, B4.y, B4.z, B4.w};
    ushortx8 h, l;
#pragma unroll
    for (int j = 0; j < 8; ++j) {
        unsigned short hh, ll;
        split1(f[j], hh, ll);
        h[j] = hh; l[j] = ll;
    }
    *(ushortx8*)hi = h;
    *(ushortx8*)lo = l;
}

// ---- one-time per call: split ALL layers' weights into bf16 hi/lo planes and
// precompute Aneg = -exp(A_log). Pure streaming, ~680 MB.
__global__ __launch_bounds__(256) void k_prep(
    const float* __restrict__ xz_w, const float* __restrict__ op_w,
    const float* __restrict__ A_log,
    ushort_t* __restrict__ xzw_hi, ushort_t* __restrict__ xzw_lo,
    ushort_t* __restrict__ opw_hi, ushort_t* __restrict__ opw_lo,
    float* __restrict__ Aneg)
{
    const long total = XZ_ALL + OP_ALL + AN_ALL;
    long g = (long)blockIdx.x * 256 + threadIdx.x;
    const long stride = (long)gridDim.x * 256;
    for (; g < total; g += stride) {
        if (g < XZ_ALL) {
            split8(xz_w + g * 8, xzw_hi + g * 8, xzw_lo + g * 8);
        } else if (g < XZ_ALL + OP_ALL) {
            const long r = g - XZ_ALL;
            split8(op_w + r * 8, opw_hi + r * 8, opw_lo + r * 8);
        } else {
            const long r = g - XZ_ALL - OP_ALL;
            const float* s = A_log + r * 8;
            float* d = Aneg + r * 8;
#pragma unroll
            for (int j = 0; j < 8; ++j) d[j] = -__expf(s[j]);
        }
    }
}

// ---- in_proj fp32 GEMM (M=512,N=768,K=64) -> h hi/lo planes
__global__ __launch_bounds__(256) void k_inproj(
    const float* __restrict__ A, const float* __restrict__ W,
    const float* __restrict__ bias,
    ushort_t* __restrict__ Chi, ushort_t* __restrict__ Clo)
{
    __shared__ float As[16][68];
    __shared__ float Ws[16][68];
    const int tid = threadIdx.x;
    const int tx = tid & 15, ty = tid >> 4;
    const int bn0 = blockIdx.x * 64, bm0 = blockIdx.y * 64;
    float acc[4][4] = {};
    for (int k0 = 0; k0 < D_IN; k0 += 16) {
        int r = tid >> 2, c = (tid & 3) << 2;
        float4 a4 = *(const float4*)(A + (size_t)(bm0 + r) * D_IN + k0 + c);
        As[c + 0][r] = a4.x; As[c + 1][r] = a4.y;
        As[c + 2][r] = a4.z; As[c + 3][r] = a4.w;
        float4 w4 = *(const float4*)(W + (size_t)(bn0 + r) * D_IN + k0 + c);
        Ws[c + 0][r] = w4.x; Ws[c + 1][r] = w4.y;
        Ws[c + 2][r] = w4.z; Ws[c + 3][r] = w4.w;
        __syncthreads();
#pragma unroll
        for (int kk = 0; kk < 16; ++kk) {
            float af[4], wf[4];
#pragma unroll
            for (int i = 0; i < 4; ++i) af[i] = As[kk][ty * 4 + i];
#pragma unroll
            for (int j = 0; j < 4; ++j) wf[j] = Ws[kk][tx * 4 + j];
#pragma unroll
            for (int i = 0; i < 4; ++i)
#pragma unroll
                for (int j = 0; j < 4; ++j) acc[i][j] += af[i] * wf[j];
        }
        __syncthreads();
    }
#pragma unroll
    for (int i = 0; i < 4; ++i) {
        const int bb = bm0 + ty * 4 + i;
#pragma unroll
        for (int j = 0; j < 4; ++j) {
            const int n = bn0 + tx * 4 + j;
            float v = acc[i][j] + bias[n];
            const size_t idx = (size_t)bb * D_MODEL + n;
            unsigned short hh, ll;
            split1(v, hh, ll);
            Chi[idx] = hh;
            Clo[idx] = ll;
        }
    }
}

// ---- bf16x3 MFMA GEMM, 64x64 tile, 4 waves of 32x32, BK=32, dbuf LDS.
// XCD-aware block map: blocks sharing a W col-tile share bid%8 (same XCD L2)
// so each W byte is fetched from HBM once, not 8x (default round-robin).
// MODE 0: xz (K=768, 384 blocks) + conv/silu epilogue -> x, g=silu-gate(z)
// MODE 1: outproj (K=1536, 96 blocks) -> h fp32 + h hi/lo planes
template<int MODE>
__global__ __launch_bounds__(256) void k_gemm(
    const ushort_t* __restrict__ Ahi, const ushort_t* __restrict__ Alo,
    const ushort_t* __restrict__ Whi, const ushort_t* __restrict__ Wlo,
    float* __restrict__ xout, float* __restrict__ gout,
    float* __restrict__ hout, ushort_t* __restrict__ Chi, ushort_t* __restrict__ Clo,
    const float* __restrict__ conv_state, const float* __restrict__ conv_w,
    const float* __restrict__ conv_b)
{
    constexpr int K = (MODE == 0) ? D_MODEL : D_INNER;
    constexpr int nk = K / 32;
    const int bid = blockIdx.x;
    int c, r;
    if (MODE == 0) {             // 48 col-tiles x 8 row-tiles
        c = (bid & 7) + ((bid >> 6) << 3);
        r = (bid >> 3) & 7;
    } else {                     // 12 col-tiles x 8 row-tiles
        if (bid < 64) { c = bid & 7; r = bid >> 3; }
        else { const int j = bid - 64; c = 8 + (j & 3); r = j >> 2; }
    }
    const int bn0 = c * 64, bm0 = r * 64;

    __shared__ __align__(16) unsigned short As[2][64 * 64];
    __shared__ __align__(16) unsigned short Bs[2][64 * 64];

    const int t = threadIdx.x;
    const int sr = t >> 2, s0 = t & 3;
    const int lane = t & 63, wv = t >> 6;
    const int wm = wv >> 1, wn = wv & 1;
    const int ln15 = lane & 15, kq = lane >> 4;

    const ushort_t* Ah = Ahi + (size_t)(bm0 + sr) * K + s0 * 8;
    const ushort_t* Al = Alo + (size_t)(bm0 + sr) * K + s0 * 8;
    const ushort_t* Wh = Whi + (size_t)(bn0 + sr) * K + s0 * 8;
    const ushort_t* Wl = Wlo + (size_t)(bn0 + sr) * K + s0 * 8;

    f32x4 acc[2][2];
#pragma unroll
    for (int m = 0; m < 2; ++m)
#pragma unroll
        for (int n = 0; n < 2; ++n) acc[m][n] = (f32x4){0.f, 0.f, 0.f, 0.f};

    const int sw = sr & 7;
    auto stage = [&](ushortx8 hi, ushortx8 lo, unsigned short* S) {
        *(ushortx8*)&S[sr * 64 + ((s0 ^ sw) << 3)] = hi;
        *(ushortx8*)&S[sr * 64 + (((s0 + 4) ^ sw) << 3)] = lo;
    };

    ushortx8 pah = *(const ushortx8*)Ah;
    ushortx8 pal = *(const ushortx8*)Al;
    ushortx8 pwh = *(const ushortx8*)Wh;
    ushortx8 pwl = *(const ushortx8*)Wl;
    stage(pah, pal, As[0]);
    stage(pwh, pwl, Bs[0]);

    for (int kb = 0; kb < nk; ++kb) {
        __syncthreads();
        const int cur = kb & 1;
        if (kb + 1 < nk) {
            const int ko = (kb + 1) << 5;
            pah = *(const ushortx8*)(Ah + ko);
            pal = *(const ushortx8*)(Al + ko);
            pwh = *(const ushortx8*)(Wh + ko);
            pwl = *(const ushortx8*)(Wl + ko);
        }
        bf16x8 ah[2], al2[2], bh[2], bl[2];
#pragma unroll
        for (int m = 0; m < 2; ++m) {
            const int rr = wm * 32 + m * 16 + ln15;
            const int base = rr * 64;
            const int rs = rr & 7;
            ah[m]  = __builtin_bit_cast(bf16x8, *(ushortx8*)&As[cur][base + ((kq ^ rs) << 3)]);
            al2[m] = __builtin_bit_cast(bf16x8, *(ushortx8*)&As[cur][base + (((kq + 4) ^ rs) << 3)]);
        }
#pragma unroll
        for (int n = 0; n < 2; ++n) {
            const int rr = wn * 32 + n * 16 + ln15;
            const int base = rr * 64;
            const int rs = rr & 7;
            bh[n] = __builtin_bit_cast(bf16x8, *(ushortx8*)&Bs[cur][base + ((kq ^ rs) << 3)]);
            bl[n] = __builtin_bit_cast(bf16x8, *(ushortx8*)&Bs[cur][base + (((kq + 4) ^ rs) << 3)]);
        }
#pragma unroll
        for (int m = 0; m < 2; ++m)
#pragma unroll
            for (int n = 0; n < 2; ++n) {
                acc[m][n] = __builtin_amdgcn_mfma_f32_16x16x32_bf16(ah[m],  bh[n], acc[m][n], 0, 0, 0);
                acc[m][n] = __builtin_amdgcn_mfma_f32_16x16x32_bf16(ah[m],  bl[n], acc[m][n], 0, 0, 0);
                acc[m][n] = __builtin_amdgcn_mfma_f32_16x16x32_bf16(al2[m], bh[n], acc[m][n], 0, 0, 0);
            }
        if (kb + 1 < nk) {
            stage(pah, pal, As[cur ^ 1]);
            stage(pwh, pwl, Bs[cur ^ 1]);
        }
    }

    // epilogue: C/D frag mapping col=lane&15, row=(lane>>4)*4+j
#pragma unroll
    for (int m = 0; m < 2; ++m) {
#pragma unroll
        for (int n = 0; n < 2; ++n) {
            const int col = bn0 + wn * 32 + n * 16 + ln15;
            const int row0 = bm0 + wm * 32 + m * 16 + kq * 4;
            f32x4 v = acc[m][n];
            if (MODE == 0) {
                if (col < D_INNER) {
                    const float4 cwv = *(const float4*)(conv_w + (size_t)col * 4);
                    const float cbv = conv_b[col];
#pragma unroll
                    for (int j = 0; j < 4; ++j) {
                        const int row = row0 + j;
                        const float4 csv = *(const float4*)(conv_state + ((size_t)row * D_INNER + col) * 4);
                        float cc = csv.y * cwv.x + csv.z * cwv.y + csv.w * cwv.z
                                 + v[j] * cwv.w + cbv;
                        xout[(size_t)row * D_INNER + col] = cc * sigmoidf_(cc);
                    }
                } else {
#pragma unroll
                    for (int j = 0; j < 4; ++j) {
                        float zv = v[j];
                        gout[(size_t)(row0 + j) * D_INNER + (col - D_INNER)] = zv * sigmoidf_(zv);
                    }
                }
            } else {
#pragma unroll
                for (int j = 0; j < 4; ++j) {
                    const size_t idx = (size_t)(row0 + j) * D_MODEL + col;
                    float val = v[j];
                    hout[idx] = val;
                    unsigned short hh, ll;
                    split1(val, hh, ll);
                    Chi[idx] = hh;
                    Clo[idx] = ll;
                }
            }
        }
    }
}

// ---- fused xproj + dt + softplus + SSM + gate; 2 batch rows per block
__global__ __launch_bounds__(256) void k_bc(
    const float* __restrict__ x, const float* __restrict__ g,
    const float* __restrict__ xproj_w, const float* __restrict__ dtproj_w,
    const float* __restrict__ dtproj_b, const float* __restrict__ Aneg_l,
    const float* __restrict__ Dp, const float* __restrict__ ssm,
    ushort_t* __restrict__ yhi, ushort_t* __restrict__ ylo)
{
    __shared__ __align__(16) float xs0[D_INNER];
    __shared__ __align__(16) float xs1[D_INNER];
    __shared__ float xdb0[XDB_DIM];
    __shared__ float xdb1[XDB_DIM];
    const int tid = threadIdx.x;
    const int b0 = blockIdx.x * 2, b1 = b0 + 1;

    {
        const float4* xr0 = (const float4*)(x + (size_t)b0 * D_INNER);
        const float4* xr1 = (const float4*)(x + (size_t)b1 * D_INNER);
        float4* d0 = (float4*)xs0; float4* d1 = (float4*)xs1;
        for (int i = tid; i < D_INNER / 4; i += 256) { d0[i] = xr0[i]; d1[i] = xr1[i]; }
    }
    __syncthreads();

    const int lane = tid & 63, wv = tid >> 6;
    const float4* xs40 = (const float4*)xs0;
    const float4* xs41 = (const float4*)xs1;
    for (int n = wv; n < XDB_DIM; n += 4) {
        const float4* wr = (const float4*)(xproj_w + (size_t)n * D_INNER);
        float s0 = 0.f, s1 = 0.f;
#pragma unroll
        for (int j = 0; j < D_INNER / 4 / 64; ++j) {
            float4 w = wr[lane + 64 * j];
            float4 u = xs40[lane + 64 * j];
            float4 q = xs41[lane + 64 * j];
            s0 += w.x * u.x + w.y * u.y + w.z * u.z + w.w * u.w;
            s1 += w.x * q.x + w.y * q.y + w.z * q.z + w.w * q.w;
        }
#pragma unroll
        for (int off = 32; off > 0; off >>= 1) { s0 += __shfl_xor(s0, off); s1 += __shfl_xor(s1, off); }
        if (lane == 0) { xdb0[n] = s0; xdb1[n] = s1; }
    }
    __syncthreads();

    float B0[16], C0[16], B1[16], C1[16];
#pragma unroll
    for (int n = 0; n < 16; ++n) {
        B0[n] = xdb0[DT_RANK + n]; C0[n] = xdb0[DT_RANK + 16 + n];
        B1[n] = xdb1[DT_RANK + n]; C1[n] = xdb1[DT_RANK + 16 + n];
    }

    for (int d = tid; d < D_INNER; d += 256) {
        const float4* dtw = (const float4*)(dtproj_w + (size_t)d * DT_RANK);
        float s0 = 0.f, s1 = 0.f;
#pragma unroll
        for (int j = 0; j < DT_RANK / 4; ++j) {
            float4 w = dtw[j];
            s0 += w.x * xdb0[4*j] + w.y * xdb0[4*j+1] + w.z * xdb0[4*j+2] + w.w * xdb0[4*j+3];
            s1 += w.x * xdb1[4*j] + w.y * xdb1[4*j+1] + w.z * xdb1[4*j+2] + w.w * xdb1[4*j+3];
        }
        const float bb = dtproj_b[d];
        s0 += bb; s1 += bb;
        float dt0 = fmaxf(s0, 0.f) + log1pf(__expf(-fabsf(s0)));
        float dt1 = fmaxf(s1, 0.f) + log1pf(__expf(-fabsf(s1)));
        const float xv0 = xs0[d], xv1 = xs1[d];
        const float dtx0 = dt0 * xv0, dtx1 = dt1 * xv1;
        const float4* anp = (const float4*)(Aneg_l + (size_t)d * D_STATE);
        const float4* sp0 = (const float4*)(ssm + ((size_t)b0 * D_INNER + d) * D_STATE);
        const float4* sp1 = (const float4*)(ssm + ((size_t)b1 * D_INNER + d) * D_STATE);
        float y0 = 0.f, y1 = 0.f;
#pragma unroll
        for (int q = 0; q < 4; ++q) {
            float4 an = anp[q];
            float4 u = sp0[q];
            float4 w = sp1[q];
            float e;
            e = __expf(dt0 * an.x); y0 += (u.x * e + dtx0 * B0[4*q+0]) * C0[4*q+0];
            e = __expf(dt0 * an.y); y0 += (u.y * e + dtx0 * B0[4*q+1]) * C0[4*q+1];
            e = __expf(dt0 * an.z); y0 += (u.z * e + dtx0 * B0[4*q+2]) * C0[4*q+2];
            e = __expf(dt0 * an.w); y0 += (u.w * e + dtx0 * B0[4*q+3]) * C0[4*q+3];
            e = __expf(dt1 * an.x); y1 += (w.x * e + dtx1 * B1[4*q+0]) * C1[4*q+0];
            e = __expf(dt1 * an.y); y1 += (w.y * e + dtx1 * B1[4*q+1]) * C1[4*q+1];
            e = __expf(dt1 * an.z); y1 += (w.z * e + dtx1 * B1[4*q+2]) * C1[4*q+2];
            e = __expf(dt1 * an.w); y1 += (w.w * e + dtx1 * B1[4*q+3]) * C1[4*q+3];
        }
        const float dv = Dp[d];
        y0 += dv * xv0; y1 += dv * xv1;
        const float o0 = y0 * g[(size_t)b0 * D_INNER + d];
        const float o1 = y1 * g[(size_t)b1 * D_INNER + d];
        unsigned short hh, ll;
        split1(o0, hh, ll);
        yhi[(size_t)b0 * D_INNER + d] = hh; ylo[(size_t)b0 * D_INNER + d] = ll;
        split1(o1, hh, ll);
        yhi[(size_t)b1 * D_INNER + d] = hh; ylo[(size_t)b1 * D_INNER + d] = ll;
    }
}

// ---- LayerNorm, one block per row
__global__ __launch_bounds__(256) void k_ln(
    const float* __restrict__ h, const float* __restrict__ gam,
    const float* __restrict__ bet, float* __restrict__ out)
{
    const int b = blockIdx.x;
    const int tid = threadIdx.x;
    float v[3];
#pragma unroll
    for (int j = 0; j < 3; ++j) v[j] = h[(size_t)b * D_MODEL + tid + j * 256];
    float s = v[0] + v[1] + v[2];
    float s2 = v[0] * v[0] + v[1] * v[1] + v[2] * v[2];
#pragma unroll
    for (int off = 32; off > 0; off >>= 1) {
        s += __shfl_xor(s, off);
        s2 += __shfl_xor(s2, off);
    }
    __shared__ float red[8];
    const int lane = tid & 63, wv = tid >> 6;
    if (lane == 0) { red[wv] = s; red[4 + wv] = s2; }
    __syncthreads();
    s = red[0] + red[1] + red[2] + red[3];
    s2 = red[4] + red[5] + red[6] + red[7];
    const float mu = s * (1.f / D_MODEL);
    const float var = s2 * (1.f / D_MODEL) - mu * mu;
    const float inv = 1.f / sqrtf(var + 1e-5f);
#pragma unroll
    for (int j = 0; j < 3; ++j) {
        int c = tid + j * 256;
        out[(size_t)b * D_MODEL + c] = (v[j] - mu) * inv * gam[c] + bet[c];
    }
}

extern "C" void kernel_launch(void* const* d_in, const int* in_sizes, int n_in,
                              void* d_out, int out_size, void* d_ws, size_t ws_size,
                              hipStream_t stream)
{
    const float* x_t        = (const float*)d_in[0];
    const float* in_w       = (const float*)d_in[1];
    const float* in_b       = (const float*)d_in[2];
    const float* xz_w       = (const float*)d_in[3];
    const float* conv_w     = (const float*)d_in[4];
    const float* conv_b     = (const float*)d_in[5];
    const float* xproj_w    = (const float*)d_in[6];
    const float* dtproj_w   = (const float*)d_in[7];
    const float* dtproj_b   = (const float*)d_in[8];
    const float* A_log      = (const float*)d_in[9];
    const float* Dvec       = (const float*)d_in[10];
    const float* outproj_w  = (const float*)d_in[11];
    const float* conv_state = (const float*)d_in[12];
    const float* ssm_state  = (const float*)d_in[13];
    const float* ln_g       = (const float*)d_in[14];
    const float* ln_b       = (const float*)d_in[15];

    float* ws = (float*)d_ws;
    float* h    = ws;                                // 512*768
    float* x    = h + (size_t)BATCH * D_MODEL;       // 512*1536
    float* g    = x + (size_t)BATCH * D_INNER;       // 512*1536 (silu-gated z)
    float* Aneg = g + (size_t)BATCH * D_INNER;       // 24*1536*16
    ushort_t* h_hi = (ushort_t*)(Aneg + (size_t)DEPTH * D_INNER * D_STATE);
    ushort_t* h_lo = h_hi + (size_t)BATCH * D_MODEL;
    ushort_t* y_hi = h_lo + (size_t)BATCH * D_MODEL;
    ushort_t* y_lo = y_hi + (size_t)BATCH * D_INNER;
    ushort_t* xzw_hi = y_lo + (size_t)BATCH * D_INNER;
    ushort_t* xzw_lo = xzw_hi + (size_t)DEPTH * XZW_N;
    ushort_t* opw_hi = xzw_lo + (size_t)DEPTH * XZW_N;
    ushort_t* opw_lo = opw_hi + (size_t)DEPTH * OPW_N;

    dim3 blk(256);

    k_prep<<<dim3(2048), blk, 0, stream>>>(
        xz_w, outproj_w, A_log, xzw_hi, xzw_lo, opw_hi, opw_lo, Aneg);

    k_inproj<<<dim3(12, 8), blk, 0, stream>>>(x_t, in_w, in_b, h_hi, h_lo);

    for (int l = 0; l < DEPTH; ++l) {
        const ushort_t* xzh = xzw_hi + (size_t)l * XZW_N;
        const ushort_t* xzl = xzw_lo + (size_t)l * XZW_N;
        const ushort_t* oph = opw_hi + (size_t)l * OPW_N;
        const ushort_t* opl = opw_lo + (size_t)l * OPW_N;
        const float* csl = conv_state + (size_t)l * BATCH * D_INNER * D_CONV;
        const float* cwl = conv_w + (size_t)l * D_INNER * D_CONV;
        const float* cbl = conv_b + (size_t)l * D_INNER;
        const float* xpl = xproj_w + (size_t)l * XDB_DIM * D_INNER;
        const float* dwl = dtproj_w + (size_t)l * D_INNER * DT_RANK;
        const float* dbl = dtproj_b + (size_t)l * D_INNER;
        const float* anl = Aneg + (size_t)l * D_INNER * D_STATE;
        const float* dpl = Dvec + (size_t)l * D_INNER;
        const float* ssl = ssm_state + (size_t)l * BATCH * D_INNER * D_STATE;

        k_gemm<0><<<dim3(384), blk, 0, stream>>>(
            h_hi, h_lo, xzh, xzl, x, g, nullptr, nullptr, nullptr,
            csl, cwl, cbl);

        k_bc<<<dim3(256), blk, 0, stream>>>(
            x, g, xpl, dwl, dbl, anl, dpl, ssl, y_hi, y_lo);

        k_gemm<1><<<dim3(96), blk, 0, stream>>>(
            y_hi, y_lo, oph, opl, nullptr, nullptr, h, h_hi, h_lo,
            nullptr, nullptr, nullptr);
    }

    k_ln<<<dim3(BATCH), blk, 0, stream>>>(h, ln_g, ln_b, (float*)d_out);
}